// Round 2
// baseline (2233.384 us; speedup 1.0000x reference)
//
#include <hip/hip_runtime.h>
#include <hip/hip_bf16.h>
#include <math.h>

#define B_ 2
#define L_ 2048
#define D_ 1024
#define H_ 4
#define NC 64   // chunks per sequence

__device__ __forceinline__ float wred(float v) {
    v += __shfl_down(v, 32);
    v += __shfl_down(v, 16);
    v += __shfl_down(v, 8);
    v += __shfl_down(v, 4);
    v += __shfl_down(v, 2);
    v += __shfl_down(v, 1);
    return v;
}

// ---------------------------------------------------------------- GEMM
// C[M,N] = act(A[M,K] @ B[K,N] + bias). 64x64 tile, BK=16, 256 thr, 4x4 micro.
template <int ACT>
__global__ __launch_bounds__(256) void gemm_k(const float* __restrict__ A,
                                              const float* __restrict__ Bw,
                                              const float* __restrict__ bias,
                                              float* __restrict__ Cb,
                                              int M, int N, int K) {
    __shared__ __align__(16) float As[16][68];
    __shared__ __align__(16) float Bs[16][68];
    const int t = threadIdx.x;
    const int tx = t & 15, ty = t >> 4;
    const int m0 = blockIdx.y << 6, n0 = blockIdx.x << 6;
    float acc[4][4] = {};
    const int lam = t >> 2;          // 0..63
    const int lak = (t & 3) << 2;    // 0,4,8,12
    const int lbr = t >> 6;          // 0..3
    const int lbc = t & 63;
    for (int k0 = 0; k0 < K; k0 += 16) {
        const float* Ap = A + (size_t)(m0 + lam) * K + (k0 + lak);
        float a0 = Ap[0], a1 = Ap[1], a2 = Ap[2], a3 = Ap[3];
        As[lak + 0][lam] = a0;
        As[lak + 1][lam] = a1;
        As[lak + 2][lam] = a2;
        As[lak + 3][lam] = a3;
        const float* Bp = Bw + (size_t)(k0 + lbr) * N + (n0 + lbc);
#pragma unroll
        for (int r = 0; r < 4; ++r)
            Bs[lbr + (r << 2)][lbc] = Bp[(size_t)(r << 2) * N];
        __syncthreads();
#pragma unroll
        for (int kk = 0; kk < 16; ++kk) {
            const float4 av = *(const float4*)&As[kk][ty << 2];
            const float4 bv = *(const float4*)&Bs[kk][tx << 2];
            acc[0][0] += av.x * bv.x; acc[0][1] += av.x * bv.y;
            acc[0][2] += av.x * bv.z; acc[0][3] += av.x * bv.w;
            acc[1][0] += av.y * bv.x; acc[1][1] += av.y * bv.y;
            acc[1][2] += av.y * bv.z; acc[1][3] += av.y * bv.w;
            acc[2][0] += av.z * bv.x; acc[2][1] += av.z * bv.y;
            acc[2][2] += av.z * bv.z; acc[2][3] += av.z * bv.w;
            acc[3][0] += av.w * bv.x; acc[3][1] += av.w * bv.y;
            acc[3][2] += av.w * bv.z; acc[3][3] += av.w * bv.w;
        }
        __syncthreads();
    }
#pragma unroll
    for (int i = 0; i < 4; ++i) {
        const int m = m0 + (ty << 2) + i;
#pragma unroll
        for (int j = 0; j < 4; ++j) {
            const int n = n0 + (tx << 2) + j;
            float v = acc[i][j];
            if (bias) v += bias[n];
            if (ACT == 1) v = 0.5f * v * (1.0f + erff(v * 0.70710678118654752f));
            Cb[(size_t)m * N + n] = v;
        }
    }
}

// ------------------------------------------------- causal depthwise conv (+silu)
template <int KW, int SILU>
__global__ __launch_bounds__(256) void conv_k(const float* __restrict__ x,
                                              const float* __restrict__ w,
                                              float* __restrict__ y) {
    const int idx = blockIdx.x * 256 + threadIdx.x;  // over B*L*D
    const int c = idx & (D_ - 1);
    const int l = (idx >> 10) & (L_ - 1);
    float acc = 0.f;
#pragma unroll
    for (int tap = 0; tap < KW; ++tap) {
        const int off = tap - (KW - 1);
        if (l + off >= 0) acc += x[idx + off * D_] * w[c * KW + tap];
    }
    if (SILU) acc = acc / (1.f + expf(-acc));  // x*sigmoid(x)
    y[idx] = acc;
}

// -------------------------------------------------------------- beta = sigmoid(hs @ b_w)
__global__ __launch_bounds__(64) void beta_k(const float* __restrict__ hs,
                                             const float* __restrict__ bw,
                                             float* __restrict__ beta) {
    const int row = blockIdx.x;  // b*L + l
    const int lane = threadIdx.x;
    float a0 = 0, a1 = 0, a2 = 0, a3 = 0;
    const float* hp = hs + (size_t)row * D_;
    for (int c = lane; c < D_; c += 64) {
        const float x = hp[c];
        a0 += x * bw[c * 4 + 0];
        a1 += x * bw[c * 4 + 1];
        a2 += x * bw[c * 4 + 2];
        a3 += x * bw[c * 4 + 3];
    }
    a0 = wred(a0); a1 = wred(a1); a2 = wred(a2); a3 = wred(a3);
    if (lane == 0) {
        float* o = beta + (size_t)row * 4;
        o[0] = 1.f / (1.f + expf(-a0));
        o[1] = 1.f / (1.f + expf(-a1));
        o[2] = 1.f / (1.f + expf(-a2));
        o[3] = 1.f / (1.f + expf(-a3));
    }
}

// -------------------------------------------------------------- l2norm rows of 256
__global__ __launch_bounds__(64) void l2norm_k(float* __restrict__ x) {
    float* p = x + (size_t)blockIdx.x * 256 + threadIdx.x * 4;
    float4 v = *(float4*)p;
    float ss = v.x * v.x + v.y * v.y + v.z * v.z + v.w * v.w;
    ss = wred(ss);
    ss = __shfl(ss, 0);
    const float s = rsqrtf(ss + 1e-6f);
    v.x *= s; v.y *= s; v.z *= s; v.w *= s;
    *(float4*)p = v;
}

// ---------------------------------- per-chunk UT transform: T=(I-A)^-1, w=T@kb, u=T@(v*beta)
__global__ __launch_bounds__(256) void prep_k(const float* __restrict__ kg,
                                              const float* __restrict__ vg,
                                              const float* __restrict__ beta,
                                              float* __restrict__ wb,
                                              float* __restrict__ ub) {
    __shared__ float lk[32 * 257];
    __shared__ float Am[32 * 33];
    __shared__ float Tm[32 * 33];
    __shared__ float lbeta[32];
    const int bid = blockIdx.x;  // B*H*NC
    const int bh = bid >> 6, ci = bid & 63;
    const int b = bh >> 2, h = bh & 3;
    const int t = threadIdx.x;
    const size_t gbase = ((size_t)(b * L_ + ci * 32)) * D_ + h * 256;
    for (int e = t; e < 8192; e += 256) {
        const int r = e >> 8, c = e & 255;
        lk[r * 257 + c] = kg[gbase + (size_t)r * D_ + c];
    }
    if (t < 32) lbeta[t] = beta[(size_t)(b * L_ + ci * 32 + t) * 4 + h];
    __syncthreads();
    // A = -tril(kb @ k^T, -1)
    for (int e = t; e < 1024; e += 256) {
        const int i = e >> 5, j = e & 31;
        float v = 0.f;
        if (j < i) {
            float d = 0.f;
            for (int c = 0; c < 256; ++c) d += lk[i * 257 + c] * lk[j * 257 + c];
            v = -lbeta[i] * d;
        }
        Am[i * 33 + j] = v;
        Tm[i * 33 + j] = (i == j) ? 1.f : 0.f;
    }
    __syncthreads();
    // forward substitution: T[i] = e_i + sum_{j<i} A[i][j] T[j]
    for (int i = 1; i < 32; ++i) {
        if (t < 32) {
            float s = 0.f;
            for (int j = 0; j < i; ++j) s += Am[i * 33 + j] * Tm[j * 33 + t];
            Tm[i * 33 + t] += s;
        }
        __syncthreads();
    }
    const size_t obase = (size_t)bid * 8192;
    // w = T @ (beta*k)
    for (int e = t; e < 8192; e += 256) {
        const int i = e >> 8, d = e & 255;
        float s = 0.f;
        for (int j = 0; j <= i; ++j) s += Tm[i * 33 + j] * lbeta[j] * lk[j * 257 + d];
        wb[obase + e] = s;
    }
    __syncthreads();
    for (int e = t; e < 8192; e += 256) {  // overwrite stage with v*beta
        const int r = e >> 8, c = e & 255;
        lk[r * 257 + c] = vg[gbase + (size_t)r * D_ + c] * lbeta[r];
    }
    __syncthreads();
    // u = T @ (v*beta)
    for (int e = t; e < 8192; e += 256) {
        const int i = e >> 8, d = e & 255;
        float s = 0.f;
        for (int j = 0; j <= i; ++j) s += Tm[i * 33 + j] * lk[j * 257 + d];
        ub[obase + e] = s;
    }
}

// -------------------------------------------------- attn = tril(q @ k^T) per chunk
__global__ __launch_bounds__(256) void attn_k(const float* __restrict__ qg,
                                              const float* __restrict__ kg,
                                              float* __restrict__ attn) {
    __shared__ float lk[32 * 257];
    const int bid = blockIdx.x;
    const int bh = bid >> 6, ci = bid & 63;
    const int b = bh >> 2, h = bh & 3;
    const int t = threadIdx.x;
    const size_t gbase = ((size_t)(b * L_ + ci * 32)) * D_ + h * 256;
    for (int e = t; e < 8192; e += 256) {
        const int r = e >> 8, c = e & 255;
        lk[r * 257 + c] = kg[gbase + (size_t)r * D_ + c];
    }
    __syncthreads();
    for (int e = t; e < 1024; e += 256) {
        const int i = e >> 5, j = e & 31;
        float v = 0.f;
        if (j <= i) {
            const float* qp = qg + gbase + (size_t)i * D_;
            for (int c = 0; c < 256; ++c) v += qp[c] * lk[j * 257 + c];
        }
        attn[(size_t)bid * 1024 + e] = v;
    }
}

// ------------------------------------------ sequential scan over chunks, dv split 16-wide
__global__ __launch_bounds__(256) void scan_k(const float* __restrict__ qg,
                                              const float* __restrict__ kg,
                                              const float* __restrict__ wbuf,
                                              const float* __restrict__ ubuf,
                                              const float* __restrict__ attn,
                                              float* __restrict__ dlt) {
    __shared__ __align__(16) float stage[32 * 260];  // reused: w, then q, then k
    __shared__ float Sm[256 * 16];                   // state slice S[dk][16]
    __shared__ float attn_s[32 * 33];
    __shared__ float u_s[32 * 17];
    __shared__ float uh[32 * 17];
    const int t = threadIdx.x;
    const int bh = blockIdx.x & 7;     // %8 -> same (b,h) tiles share an XCD
    const int tile = blockIdx.x >> 3;  // 0..15
    const int b = bh >> 2, h = bh & 3;
    for (int e = t; e < 4096; e += 256) Sm[e] = 0.f;
    __syncthreads();
    const int d = t & 15, iq = t >> 4;  // iq 0..15
    for (int ci = 0; ci < NC; ++ci) {
        const size_t gbase = ((size_t)(b * L_ + ci * 32)) * D_ + h * 256;
        const size_t cbase = ((size_t)(bh * NC + ci)) * 8192;
        for (int e = t; e < 512; e += 256) {
            const int r = e >> 4, dd = e & 15;
            u_s[r * 17 + dd] = ubuf[cbase + r * 256 + tile * 16 + dd];
        }
        for (int e = t; e < 1024; e += 256)
            attn_s[(e >> 5) * 33 + (e & 31)] = attn[((size_t)(bh * NC + ci)) * 1024 + e];
        for (int e = t; e < 2048; e += 256) {  // stage w
            const int r = e >> 6, c4 = (e & 63) << 2;
            *(float4*)&stage[r * 260 + c4] = *(const float4*)&wbuf[cbase + r * 256 + c4];
        }
        __syncthreads();
        // phase 1: u_hat = u - w @ S
#pragma unroll
        for (int rep = 0; rep < 2; ++rep) {
            const int i = iq + rep * 16;
            float acc = 0.f;
            for (int c = 0; c < 256; c += 4) {
                const float4 wv = *(const float4*)&stage[i * 260 + c];
                acc += wv.x * Sm[(c + 0) * 16 + d] + wv.y * Sm[(c + 1) * 16 + d] +
                       wv.z * Sm[(c + 2) * 16 + d] + wv.w * Sm[(c + 3) * 16 + d];
            }
            uh[i * 17 + d] = u_s[i * 17 + d] - acc;
        }
        __syncthreads();
        for (int e = t; e < 2048; e += 256) {  // stage q
            const int r = e >> 6, c4 = (e & 63) << 2;
            *(float4*)&stage[r * 260 + c4] = *(const float4*)&qg[gbase + (size_t)r * D_ + c4];
        }
        __syncthreads();
        // phase 2: o = q @ S + attn @ u_hat
#pragma unroll
        for (int rep = 0; rep < 2; ++rep) {
            const int i = iq + rep * 16;
            float acc = 0.f;
            for (int c = 0; c < 256; c += 4) {
                const float4 qv = *(const float4*)&stage[i * 260 + c];
                acc += qv.x * Sm[(c + 0) * 16 + d] + qv.y * Sm[(c + 1) * 16 + d] +
                       qv.z * Sm[(c + 2) * 16 + d] + qv.w * Sm[(c + 3) * 16 + d];
            }
            float acc2 = 0.f;
#pragma unroll
            for (int j = 0; j < 32; ++j) acc2 += attn_s[i * 33 + j] * uh[j * 17 + d];
            dlt[gbase + (size_t)i * D_ + tile * 16 + d] = acc + acc2;
        }
        __syncthreads();
        for (int e = t; e < 2048; e += 256) {  // stage k
            const int r = e >> 6, c4 = (e & 63) << 2;
            *(float4*)&stage[r * 260 + c4] = *(const float4*)&kg[gbase + (size_t)r * D_ + c4];
        }
        __syncthreads();
        // phase 3: S += k^T @ u_hat
        for (int rep = 0; rep < 16; ++rep) {
            const int c = iq * 16 + rep;
            float acc = 0.f;
#pragma unroll
            for (int i2 = 0; i2 < 32; ++i2) acc += stage[i2 * 260 + c] * uh[i2 * 17 + d];
            Sm[c * 16 + d] += acc;
        }
        __syncthreads();
    }
}

// -------------------------------------------------------------- branch stats
__global__ __launch_bounds__(64) void stats_k(const float* __restrict__ f1,
                                              const float* __restrict__ f3,
                                              const float* __restrict__ f7,
                                              const float* __restrict__ f31,
                                              const float* __restrict__ dl,
                                              const float* __restrict__ vv,
                                              float* __restrict__ stat) {
    const int row = blockIdx.x;  // (b*L+l)*H + h
    const int lane = threadIdx.x;
    const float* ptrs[6] = {f1, f3, f7, f31, dl, vv};
    const size_t base = (size_t)row * 256;
    for (int br = 0; br < 6; ++br) {
        const float4 x = *(const float4*)&ptrs[br][base + lane * 4];
        float s1 = x.x + x.y + x.z + x.w;
        float s2 = x.x * x.x + x.y * x.y + x.z * x.z + x.w * x.w;
        float sa = fabsf(x.x) + fabsf(x.y) + fabsf(x.z) + fabsf(x.w);
        s1 = wred(s1); s2 = wred(s2); sa = wred(sa);
        if (lane == 0) {
            const float m = s1 / 256.f;
            float var = (s2 - 256.f * m * m) / 255.f;
            if (var < 0.f) var = 0.f;
            float* o = &stat[(size_t)row * 24 + br * 4];
            o[0] = m;
            o[1] = sqrtf(var);
            o[2] = sa / 256.f;
            o[3] = sqrtf(s2);
        }
    }
}

// -------------------------------------------------------------- gate_in = [hs, stats]
__global__ __launch_bounds__(256) void gatein_k(const float* __restrict__ hs,
                                                const float* __restrict__ stat,
                                                float* __restrict__ gin) {
    const int idx = blockIdx.x * 256 + threadIdx.x;  // B*L*1120
    const int row = idx / 1120;
    const int j = idx - row * 1120;
    gin[idx] = (j < 1024) ? hs[(size_t)row * 1024 + j]
                          : stat[(size_t)row * 96 + (j - 1024)];
}

// ---------------------------------------------- logits (hgate @ w2 + b2) -> softmax weights
__global__ __launch_bounds__(256) void wts_k(const float* __restrict__ hg,
                                             const float* __restrict__ w2,
                                             const float* __restrict__ b2,
                                             const float* __restrict__ glt,
                                             float* __restrict__ wts) {
    const int row = blockIdx.x;
    const int h = threadIdx.x >> 6, lane = threadIdx.x & 63;
    float hv[16];
    const float* hp = hg + (size_t)row * 1024;
#pragma unroll
    for (int ii = 0; ii < 16; ++ii) hv[ii] = hp[lane + 64 * ii];
    float lg[6];
#pragma unroll
    for (int s = 0; s < 6; ++s) {
        const int j = h * 6 + s;
        float acc = 0.f;
#pragma unroll
        for (int ii = 0; ii < 16; ++ii) acc += hv[ii] * w2[(size_t)(lane + 64 * ii) * 24 + j];
        lg[s] = wred(acc);
    }
    if (lane == 0) {
        const float temp = log1pf(expf(glt[h])) + 0.5f;
        float mx = -1e30f;
#pragma unroll
        for (int s = 0; s < 6; ++s) {
            lg[s] = (lg[s] + b2[h * 6 + s]) / temp;
            mx = fmaxf(mx, lg[s]);
        }
        float se = 0.f;
#pragma unroll
        for (int s = 0; s < 6; ++s) {
            lg[s] = expf(lg[s] - mx);
            se += lg[s];
        }
        float* o = &wts[(size_t)row * 24 + h * 6];
        const float inv = 1.f / se;
#pragma unroll
        for (int s = 0; s < 6; ++s) o[s] = lg[s] * inv;
    }
}

// -------------------------------------- fused = RMSNorm(sum_s w_s * branch_s) * onorm_w
__global__ __launch_bounds__(1024) void fuse_k(const float* __restrict__ f1,
                                               const float* __restrict__ f3,
                                               const float* __restrict__ f7,
                                               const float* __restrict__ f31,
                                               const float* __restrict__ dl,
                                               const float* __restrict__ vv,
                                               const float* __restrict__ wts,
                                               const float* __restrict__ onw,
                                               float* __restrict__ fused) {
    __shared__ float wloc[24];
    __shared__ float psum[16];
    const int row = blockIdx.x, t = threadIdx.x;
    if (t < 24) wloc[t] = wts[(size_t)row * 24 + t];
    __syncthreads();
    const int h = t >> 8, dd = t & 255;
    const size_t idx = (size_t)row * 1024 + t;
    const float* ptrs[6] = {f1, f3, f7, f31, dl, vv};
    float f = 0.f;
#pragma unroll
    for (int br = 0; br < 6; ++br) f += wloc[h * 6 + br] * ptrs[br][idx];
    float ss = wred(f * f);
    const int wave = t >> 6;
    if ((t & 63) == 0) psum[wave] = ss;
    __syncthreads();
    const float tot = psum[h * 4 + 0] + psum[h * 4 + 1] + psum[h * 4 + 2] + psum[h * 4 + 3];
    const float scale = rsqrtf(tot / 256.f + 1e-5f);
    fused[idx] = f * scale * onw[dd];
}

// ================================================================ launch
extern "C" void kernel_launch(void* const* d_in, const int* in_sizes, int n_in,
                              void* d_out, int out_size, void* d_ws, size_t ws_size,
                              hipStream_t stream) {
    const float* hs   = (const float*)d_in[0];
    const float* q_w  = (const float*)d_in[1];
    const float* k_w  = (const float*)d_in[2];
    const float* v_w  = (const float*)d_in[3];
    const float* b_w  = (const float*)d_in[4];
    const float* qc_w = (const float*)d_in[5];
    const float* kc_w = (const float*)d_in[6];
    const float* vc_w = (const float*)d_in[7];
    const float* f1w  = (const float*)d_in[8];
    const float* f3w  = (const float*)d_in[9];
    const float* f7w  = (const float*)d_in[10];
    const float* f31w = (const float*)d_in[11];
    const float* w1   = (const float*)d_in[12];
    const float* b1   = (const float*)d_in[13];
    const float* w2   = (const float*)d_in[14];
    const float* b2   = (const float*)d_in[15];
    const float* glt  = (const float*)d_in[16];
    const float* onw  = (const float*)d_in[17];
    const float* o_w  = (const float*)d_in[18];
    float* out = (float*)d_out;

    const size_t SZ = (size_t)B_ * L_ * D_;  // 4,194,304
    float* qlin = (float*)d_ws;       // -> fir1 later
    float* klin = qlin + SZ;          // -> fir3 later
    float* vlin = klin + SZ;          // -> fir7 later
    float* qbuf = vlin + SZ;          // -> hgate later
    float* kbuf = qbuf + SZ;          // -> fused later
    float* vbuf = kbuf + SZ;
    float* f31b = vbuf + SZ;
    float* wb   = f31b + SZ;          // -> gate_in later (wb+ub region)
    float* ub   = wb + SZ;
    float* dlt  = ub + SZ;
    float* beta = dlt + SZ;
    float* attn = beta + (size_t)B_ * L_ * H_;
    float* stat = attn + (size_t)B_ * H_ * NC * 1024;
    float* wts  = stat + (size_t)B_ * L_ * H_ * 24;
    float* f1b = qlin;
    float* f3b = klin;
    float* f7b = vlin;
    float* hgate = qbuf;
    float* fused = kbuf;
    float* gin = wb;  // 4.59M floats fit in wb+ub (8.39M)

    const dim3 gg(16, 64);
    const int M = B_ * L_;  // 4096

    // projections
    gemm_k<0><<<gg, 256, 0, stream>>>(hs, q_w, nullptr, qlin, M, 1024, 1024);
    gemm_k<0><<<gg, 256, 0, stream>>>(hs, k_w, nullptr, klin, M, 1024, 1024);
    gemm_k<0><<<gg, 256, 0, stream>>>(hs, v_w, nullptr, vlin, M, 1024, 1024);
    beta_k<<<M, 64, 0, stream>>>(hs, b_w, beta);
    // causal short conv + silu
    conv_k<4, 1><<<16384, 256, 0, stream>>>(qlin, qc_w, qbuf);
    conv_k<4, 1><<<16384, 256, 0, stream>>>(klin, kc_w, kbuf);
    conv_k<4, 1><<<16384, 256, 0, stream>>>(vlin, vc_w, vbuf);
    // l2norm q,k
    l2norm_k<<<M * H_, 64, 0, stream>>>(qbuf);
    l2norm_k<<<M * H_, 64, 0, stream>>>(kbuf);
    // chunkwise delta rule
    prep_k<<<B_ * H_ * NC, 256, 0, stream>>>(kbuf, vbuf, beta, wb, ub);
    attn_k<<<B_ * H_ * NC, 256, 0, stream>>>(qbuf, kbuf, attn);
    scan_k<<<128, 256, 0, stream>>>(qbuf, kbuf, wb, ub, attn, dlt);
    // FIR branches on v
    conv_k<1, 0><<<16384, 256, 0, stream>>>(vbuf, f1w, f1b);
    conv_k<3, 0><<<16384, 256, 0, stream>>>(vbuf, f3w, f3b);
    conv_k<7, 0><<<16384, 256, 0, stream>>>(vbuf, f7w, f7b);
    conv_k<31, 0><<<16384, 256, 0, stream>>>(vbuf, f31w, f31b);
    // gate
    stats_k<<<M * H_, 64, 0, stream>>>(f1b, f3b, f7b, f31b, dlt, vbuf, stat);
    gatein_k<<<17920, 256, 0, stream>>>(hs, stat, gin);
    gemm_k<1><<<gg, 256, 0, stream>>>(gin, w1, b1, hgate, M, 1024, 1120);
    wts_k<<<M, 256, 0, stream>>>(hgate, w2, b2, glt, wts);
    fuse_k<<<M, 1024, 0, stream>>>(f1b, f3b, f7b, f31b, dlt, vbuf, wts, onw, fused);
    // output projection
    gemm_k<0><<<gg, 256, 0, stream>>>(fused, o_w, nullptr, out, M, 1024, 1024);
}

// Round 3
// 1222.419 us; speedup vs baseline: 1.8270x; 1.8270x over previous
//
#include <hip/hip_runtime.h>
#include <hip/hip_bf16.h>
#include <math.h>

#define B_ 2
#define L_ 2048
#define D_ 1024
#define H_ 4
#define NC 64   // chunks per sequence

typedef unsigned short ushort_t;
typedef __bf16 bf16x8 __attribute__((ext_vector_type(8)));
typedef float f32x4 __attribute__((ext_vector_type(4)));
typedef ushort_t u16x8 __attribute__((ext_vector_type(8)));

__device__ __forceinline__ ushort_t f2bs(float f) {
    __hip_bfloat16 h = __float2bfloat16(f);
    ushort_t u;
    __builtin_memcpy(&u, &h, 2);
    return u;
}
__device__ __forceinline__ float bs2f(ushort_t u) {
    unsigned int v = ((unsigned int)u) << 16;
    float f;
    __builtin_memcpy(&f, &v, 4);
    return f;
}

__device__ __forceinline__ float wred(float v) {
    v += __shfl_down(v, 32);
    v += __shfl_down(v, 16);
    v += __shfl_down(v, 8);
    v += __shfl_down(v, 4);
    v += __shfl_down(v, 2);
    v += __shfl_down(v, 1);
    return v;
}

__device__ __forceinline__ void gload16(const void* g, void* l) {
    __builtin_amdgcn_global_load_lds((const __attribute__((address_space(1))) void*)g,
                                     (__attribute__((address_space(3))) void*)l, 16, 0, 0);
}

// ------------------------------------------- transpose+cast: W[K][N] f32 -> WT[N][K] bf16
__global__ __launch_bounds__(256) void tcast_k(const float* __restrict__ W,
                                               ushort_t* __restrict__ WT, int K, int N) {
    __shared__ float tile[32 * 33];
    const int k0 = blockIdx.y << 5, n0 = blockIdx.x << 5;
    for (int e = threadIdx.x; e < 1024; e += 256)
        tile[(e >> 5) * 33 + (e & 31)] = W[(size_t)(k0 + (e >> 5)) * N + n0 + (e & 31)];
    __syncthreads();
    for (int e = threadIdx.x; e < 1024; e += 256)
        WT[(size_t)(n0 + (e >> 5)) * K + k0 + (e & 31)] = f2bs(tile[(e & 31) * 33 + (e >> 5)]);
}

// ------------------------------------------- cast f32 -> bf16 flat (n divisible by 1024)
__global__ __launch_bounds__(256) void cast_k(const float* __restrict__ x,
                                              ushort_t* __restrict__ y) {
    const int i = blockIdx.x * 256 + threadIdx.x;
    const float4 v = *(const float4*)&x[(size_t)i * 4];
    ushort4 p;
    p.x = f2bs(v.x); p.y = f2bs(v.y); p.z = f2bs(v.z); p.w = f2bs(v.w);
    *(ushort4*)&y[(size_t)i * 4] = p;
}

// ------------------------------------------- bf16 MFMA GEMM (TN): C = act(A @ Bt^T + bias)
// A[M][K] bf16, Bt[N][K] bf16, C[M][N] f32. tile 128x128, BK=32, 256 thr (4 waves, 2x2 of 64x64)
template <int ACT>
__global__ __launch_bounds__(256) void gemm_bf(const ushort_t* __restrict__ A,
                                               const ushort_t* __restrict__ Bt,
                                               const float* __restrict__ bias,
                                               float* __restrict__ C,
                                               int M, int N, int K) {
    __shared__ ushort_t As[128 * 32];
    __shared__ ushort_t Bs[128 * 32];
    const int t = threadIdx.x;
    const int wv = t >> 6, l = t & 63;
    const int m0 = blockIdx.y << 7, n0 = blockIdx.x << 7;
    const int wm = wv & 1, wn = wv >> 1;
    const int q4 = l >> 4, c16 = l & 15;
    f32x4 acc[4][4];
#pragma unroll
    for (int i = 0; i < 4; ++i)
#pragma unroll
        for (int j = 0; j < 4; ++j) {
            f32x4 z = {0.f, 0.f, 0.f, 0.f};
            acc[i][j] = z;
        }
    const int srow = (l >> 2);      // row within 16-row segment
    const int scol = (l & 3) << 3;  // k element offset (0,8,16,24)
    for (int k0 = 0; k0 < K; k0 += 32) {
        __syncthreads();
#pragma unroll
        for (int si = 0; si < 2; ++si) {
            const int s = wv * 2 + si;
            gload16(&A[(size_t)(m0 + s * 16 + srow) * K + k0 + scol], &As[s * 512]);
            gload16(&Bt[(size_t)(n0 + s * 16 + srow) * K + k0 + scol], &Bs[s * 512]);
        }
        __syncthreads();
        bf16x8 af[4], bff[4];
#pragma unroll
        for (int mi = 0; mi < 4; ++mi)
            af[mi] = *(const bf16x8*)&As[(wm * 64 + mi * 16 + c16) * 32 + q4 * 8];
#pragma unroll
        for (int ni = 0; ni < 4; ++ni)
            bff[ni] = *(const bf16x8*)&Bs[(wn * 64 + ni * 16 + c16) * 32 + q4 * 8];
#pragma unroll
        for (int mi = 0; mi < 4; ++mi)
#pragma unroll
            for (int ni = 0; ni < 4; ++ni)
                acc[mi][ni] = __builtin_amdgcn_mfma_f32_16x16x32_bf16(af[mi], bff[ni],
                                                                     acc[mi][ni], 0, 0, 0);
    }
#pragma unroll
    for (int mi = 0; mi < 4; ++mi)
#pragma unroll
        for (int ni = 0; ni < 4; ++ni)
#pragma unroll
            for (int r = 0; r < 4; ++r) {
                const int row = m0 + wm * 64 + mi * 16 + q4 * 4 + r;
                const int col = n0 + wn * 64 + ni * 16 + c16;
                float v = acc[mi][ni][r];
                if (ACT == 1) {
                    v += bias[col];
                    v = 0.5f * v * (1.0f + erff(v * 0.70710678118654752f));
                }
                C[(size_t)row * N + col] = v;
            }
}

// ------------------------------------------------- causal depthwise conv (+silu)
template <int KW, int SILU>
__global__ __launch_bounds__(256) void conv_k(const float* __restrict__ x,
                                              const float* __restrict__ w,
                                              float* __restrict__ y) {
    const int idx = blockIdx.x * 256 + threadIdx.x;  // over B*L*D
    const int c = idx & (D_ - 1);
    const int l = (idx >> 10) & (L_ - 1);
    float acc = 0.f;
#pragma unroll
    for (int tap = 0; tap < KW; ++tap) {
        const int off = tap - (KW - 1);
        if (l + off >= 0) acc += x[idx + off * D_] * w[c * KW + tap];
    }
    if (SILU) acc = acc / (1.f + expf(-acc));
    y[idx] = acc;
}

// -------------------------------------------------------------- beta = sigmoid(hs @ b_w)
__global__ __launch_bounds__(64) void beta_k(const float* __restrict__ hs,
                                             const float* __restrict__ bw,
                                             float* __restrict__ beta) {
    const int row = blockIdx.x;
    const int lane = threadIdx.x;
    float a0 = 0, a1 = 0, a2 = 0, a3 = 0;
    const float* hp = hs + (size_t)row * D_;
    for (int c = lane; c < D_; c += 64) {
        const float x = hp[c];
        a0 += x * bw[c * 4 + 0];
        a1 += x * bw[c * 4 + 1];
        a2 += x * bw[c * 4 + 2];
        a3 += x * bw[c * 4 + 3];
    }
    a0 = wred(a0); a1 = wred(a1); a2 = wred(a2); a3 = wred(a3);
    if (lane == 0) {
        float* o = beta + (size_t)row * 4;
        o[0] = 1.f / (1.f + expf(-a0));
        o[1] = 1.f / (1.f + expf(-a1));
        o[2] = 1.f / (1.f + expf(-a2));
        o[3] = 1.f / (1.f + expf(-a3));
    }
}

// -------------------------------------------------------------- l2norm rows of 256
__global__ __launch_bounds__(64) void l2norm_k(float* __restrict__ x) {
    float* p = x + (size_t)blockIdx.x * 256 + threadIdx.x * 4;
    float4 v = *(float4*)p;
    float ss = v.x * v.x + v.y * v.y + v.z * v.z + v.w * v.w;
    ss = wred(ss);
    ss = __shfl(ss, 0);
    const float s = rsqrtf(ss + 1e-6f);
    v.x *= s; v.y *= s; v.z *= s; v.w *= s;
    *(float4*)p = v;
}

// ---------------------------------- per-chunk UT transform: T=(I-A)^-1, w=T@kb, u=T@(v*beta)
__global__ __launch_bounds__(256) void prep_k(const float* __restrict__ kg,
                                              const float* __restrict__ vg,
                                              const float* __restrict__ beta,
                                              float* __restrict__ wb,
                                              float* __restrict__ ub) {
    __shared__ float lk[32 * 257];
    __shared__ float Am[32 * 33];
    __shared__ float Tm[32 * 33];
    __shared__ float lbeta[32];
    const int bid = blockIdx.x;  // B*H*NC
    const int bh = bid >> 6, ci = bid & 63;
    const int b = bh >> 2, h = bh & 3;
    const int t = threadIdx.x;
    const size_t gbase = ((size_t)(b * L_ + ci * 32)) * D_ + h * 256;
    for (int e = t; e < 8192; e += 256) {
        const int r = e >> 8, c = e & 255;
        lk[r * 257 + c] = kg[gbase + (size_t)r * D_ + c];
    }
    if (t < 32) lbeta[t] = beta[(size_t)(b * L_ + ci * 32 + t) * 4 + h];
    __syncthreads();
    for (int e = t; e < 1024; e += 256) {
        const int i = e >> 5, j = e & 31;
        float v = 0.f;
        if (j < i) {
            float d = 0.f;
            for (int c = 0; c < 256; ++c) d += lk[i * 257 + c] * lk[j * 257 + c];
            v = -lbeta[i] * d;
        }
        Am[i * 33 + j] = v;
        Tm[i * 33 + j] = (i == j) ? 1.f : 0.f;
    }
    __syncthreads();
    for (int i = 1; i < 32; ++i) {
        if (t < 32) {
            float s = 0.f;
            for (int j = 0; j < i; ++j) s += Am[i * 33 + j] * Tm[j * 33 + t];
            Tm[i * 33 + t] += s;
        }
        __syncthreads();
    }
    const size_t obase = (size_t)bid * 8192;
    for (int e = t; e < 8192; e += 256) {
        const int i = e >> 8, d = e & 255;
        float s = 0.f;
        for (int j = 0; j <= i; ++j) s += Tm[i * 33 + j] * lbeta[j] * lk[j * 257 + d];
        wb[obase + e] = s;
    }
    __syncthreads();
    for (int e = t; e < 8192; e += 256) {
        const int r = e >> 8, c = e & 255;
        lk[r * 257 + c] = vg[gbase + (size_t)r * D_ + c] * lbeta[r];
    }
    __syncthreads();
    for (int e = t; e < 8192; e += 256) {
        const int i = e >> 8, d = e & 255;
        float s = 0.f;
        for (int j = 0; j <= i; ++j) s += Tm[i * 33 + j] * lk[j * 257 + d];
        ub[obase + e] = s;
    }
}

// -------------------------------------------------- attn = tril(q @ k^T) per chunk
__global__ __launch_bounds__(256) void attn_k(const float* __restrict__ qg,
                                              const float* __restrict__ kg,
                                              float* __restrict__ attn) {
    __shared__ float lk[32 * 257];
    const int bid = blockIdx.x;
    const int bh = bid >> 6, ci = bid & 63;
    const int b = bh >> 2, h = bh & 3;
    const int t = threadIdx.x;
    const size_t gbase = ((size_t)(b * L_ + ci * 32)) * D_ + h * 256;
    for (int e = t; e < 8192; e += 256) {
        const int r = e >> 8, c = e & 255;
        lk[r * 257 + c] = kg[gbase + (size_t)r * D_ + c];
    }
    __syncthreads();
    for (int e = t; e < 1024; e += 256) {
        const int i = e >> 5, j = e & 31;
        float v = 0.f;
        if (j <= i) {
            const float* qp = qg + gbase + (size_t)i * D_;
            for (int c = 0; c < 256; ++c) v += qp[c] * lk[j * 257 + c];
        }
        attn[(size_t)bid * 1024 + e] = v;
    }
}

// ---------------------- sequential scan over chunks; dv tile = 8 (256 blocks, 1/CU)
// St[d][c] transposed state slice in LDS; w/q/k staged bf16 in padded LDS tiles.
__global__ __launch_bounds__(256) void scan2_k(const float* __restrict__ qg,
                                               const float* __restrict__ kg,
                                               const float* __restrict__ wbuf,
                                               const float* __restrict__ ubuf,
                                               const float* __restrict__ attn,
                                               float* __restrict__ dlt) {
    __shared__ ushort_t stA[32 * 264];  // w, then k
    __shared__ ushort_t stB[32 * 264];  // q
    __shared__ float St[8 * 264];       // S^T slice: [d][c] (c = dk 0..255)
    __shared__ float u_s[32 * 8];
    __shared__ float uh[32 * 8];
    __shared__ float attn_s[32 * 33];
    const int t = threadIdx.x;
    const int bh = blockIdx.x & 7;     // %8 -> spread (b,h) across XCDs
    const int tile = blockIdx.x >> 3;  // 0..31
    const int b = bh >> 2, h = bh & 3;
    const int i8 = t >> 3, d8 = t & 7;   // phase1/2 mapping: (row i, dv col d)
    const int dP3 = t >> 5, cg = t & 31; // phase3 mapping: (dv col d, c-group of 8)
    const int sr = t >> 6, sc = (t << 2) & 255;  // staging (row add, col)
    for (int e = t; e < 8 * 264; e += 256) St[e] = 0.f;
    __syncthreads();
    for (int ci = 0; ci < NC; ++ci) {
        const size_t gbase = ((size_t)(b * L_ + ci * 32)) * D_ + h * 256;
        const size_t cbase = ((size_t)(bh * NC + ci)) * 8192;
        const size_t abase = ((size_t)(bh * NC + ci)) * 1024;
        // issue w (packed) and q (strided) global loads
        float4 wr[8], qr[8];
#pragma unroll
        for (int j = 0; j < 8; ++j) {
            wr[j] = *(const float4*)&wbuf[cbase + j * 1024 + t * 4];
            qr[j] = *(const float4*)&qg[gbase + (size_t)(j * 4 + sr) * D_ + sc];
        }
        const float uv0 = ubuf[cbase + i8 * 256 + tile * 8 + d8];
        float av[4];
#pragma unroll
        for (int j = 0; j < 4; ++j) av[j] = attn[abase + j * 256 + t];
        __syncthreads();  // B1: prev phase3 done (stA free), prev phase2 done (stB free)
#pragma unroll
        for (int j = 0; j < 8; ++j) {
            ushort4 pw, pq;
            pw.x = f2bs(wr[j].x); pw.y = f2bs(wr[j].y); pw.z = f2bs(wr[j].z); pw.w = f2bs(wr[j].w);
            pq.x = f2bs(qr[j].x); pq.y = f2bs(qr[j].y); pq.z = f2bs(qr[j].z); pq.w = f2bs(qr[j].w);
            *(ushort4*)&stA[(j * 4 + sr) * 264 + sc] = pw;
            *(ushort4*)&stB[(j * 4 + sr) * 264 + sc] = pq;
        }
        u_s[t] = uv0;
#pragma unroll
        for (int j = 0; j < 4; ++j) {
            const int e = j * 256 + t;
            attn_s[(e >> 5) * 33 + (e & 31)] = av[j];
        }
        // issue k loads (consumed after phase1)
        float4 kr[8];
#pragma unroll
        for (int j = 0; j < 8; ++j)
            kr[j] = *(const float4*)&kg[gbase + (size_t)(j * 4 + sr) * D_ + sc];
        __syncthreads();  // B2: staging visible
        // phase 1: uh = u - w @ S   (thread = (i8, d8))
        {
            const ushort_t* wp = &stA[i8 * 264];
            const float* sp = &St[d8 * 264];
            float acc = 0.f;
#pragma unroll 8
            for (int c8 = 0; c8 < 32; ++c8) {
                const u16x8 wv = *(const u16x8*)&wp[c8 * 8];
                const float4 s0 = *(const float4*)&sp[c8 * 8];
                const float4 s1 = *(const float4*)&sp[c8 * 8 + 4];
                acc += bs2f(wv[0]) * s0.x + bs2f(wv[1]) * s0.y +
                       bs2f(wv[2]) * s0.z + bs2f(wv[3]) * s0.w +
                       bs2f(wv[4]) * s1.x + bs2f(wv[5]) * s1.y +
                       bs2f(wv[6]) * s1.z + bs2f(wv[7]) * s1.w;
            }
            uh[i8 * 8 + d8] = uv0 - acc;
        }
        __syncthreads();  // B3: uh ready; stA (w) free
        // write k into stA
#pragma unroll
        for (int j = 0; j < 8; ++j) {
            ushort4 pk;
            pk.x = f2bs(kr[j].x); pk.y = f2bs(kr[j].y); pk.z = f2bs(kr[j].z); pk.w = f2bs(kr[j].w);
            *(ushort4*)&stA[(j * 4 + sr) * 264 + sc] = pk;
        }
        // phase 2: o = q @ S + attn @ uh
        {
            const ushort_t* qp = &stB[i8 * 264];
            const float* sp = &St[d8 * 264];
            float acc = 0.f;
#pragma unroll 8
            for (int c8 = 0; c8 < 32; ++c8) {
                const u16x8 qv = *(const u16x8*)&qp[c8 * 8];
                const float4 s0 = *(const float4*)&sp[c8 * 8];
                const float4 s1 = *(const float4*)&sp[c8 * 8 + 4];
                acc += bs2f(qv[0]) * s0.x + bs2f(qv[1]) * s0.y +
                       bs2f(qv[2]) * s0.z + bs2f(qv[3]) * s0.w +
                       bs2f(qv[4]) * s1.x + bs2f(qv[5]) * s1.y +
                       bs2f(qv[6]) * s1.z + bs2f(qv[7]) * s1.w;
            }
            float acc2 = 0.f;
#pragma unroll
            for (int j = 0; j < 32; ++j) acc2 += attn_s[i8 * 33 + j] * uh[j * 8 + d8];
            dlt[gbase + (size_t)i8 * D_ + tile * 8 + d8] = acc + acc2;
        }
        __syncthreads();  // B4: stA=k visible; phase2's St reads done
        // phase 3: S += k^T @ uh   (thread = (dP3, cg: 8 dk cols))
        {
            float a3[8] = {0.f, 0.f, 0.f, 0.f, 0.f, 0.f, 0.f, 0.f};
            for (int i = 0; i < 32; ++i) {
                const u16x8 kv = *(const u16x8*)&stA[i * 264 + cg * 8];
                const float uv = uh[i * 8 + dP3];
#pragma unroll
                for (int j = 0; j < 8; ++j) a3[j] += bs2f(kv[j]) * uv;
            }
            float* stp = &St[dP3 * 264 + cg * 8];
#pragma unroll
            for (int j = 0; j < 8; ++j) stp[j] += a3[j];
        }
    }
}

// -------------------------------------------------------------- branch stats
__global__ __launch_bounds__(64) void stats_k(const float* __restrict__ f1,
                                              const float* __restrict__ f3,
                                              const float* __restrict__ f7,
                                              const float* __restrict__ f31,
                                              const float* __restrict__ dl,
                                              const float* __restrict__ vv,
                                              float* __restrict__ stat) {
    const int row = blockIdx.x;
    const int lane = threadIdx.x;
    const float* ptrs[6] = {f1, f3, f7, f31, dl, vv};
    const size_t base = (size_t)row * 256;
    for (int br = 0; br < 6; ++br) {
        const float4 x = *(const float4*)&ptrs[br][base + lane * 4];
        float s1 = x.x + x.y + x.z + x.w;
        float s2 = x.x * x.x + x.y * x.y + x.z * x.z + x.w * x.w;
        float sa = fabsf(x.x) + fabsf(x.y) + fabsf(x.z) + fabsf(x.w);
        s1 = wred(s1); s2 = wred(s2); sa = wred(sa);
        if (lane == 0) {
            const float m = s1 / 256.f;
            float var = (s2 - 256.f * m * m) / 255.f;
            if (var < 0.f) var = 0.f;
            float* o = &stat[(size_t)row * 24 + br * 4];
            o[0] = m;
            o[1] = sqrtf(var);
            o[2] = sa / 256.f;
            o[3] = sqrtf(s2);
        }
    }
}

// -------------------------------------------------------------- gate_in = [hs, stats] (bf16)
__global__ __launch_bounds__(256) void gatein_k(const float* __restrict__ hs,
                                                const float* __restrict__ stat,
                                                ushort_t* __restrict__ gin) {
    const int idx = blockIdx.x * 256 + threadIdx.x;  // B*L*1120
    const int row = idx / 1120;
    const int j = idx - row * 1120;
    const float v = (j < 1024) ? hs[(size_t)row * 1024 + j]
                               : stat[(size_t)row * 96 + (j - 1024)];
    gin[idx] = f2bs(v);
}

// ---------------------------------------------- logits -> softmax weights
__global__ __launch_bounds__(256) void wts_k(const float* __restrict__ hg,
                                             const float* __restrict__ w2,
                                             const float* __restrict__ b2,
                                             const float* __restrict__ glt,
                                             float* __restrict__ wts) {
    const int row = blockIdx.x;
    const int h = threadIdx.x >> 6, lane = threadIdx.x & 63;
    float hv[16];
    const float* hp = hg + (size_t)row * 1024;
#pragma unroll
    for (int ii = 0; ii < 16; ++ii) hv[ii] = hp[lane + 64 * ii];
    float lg[6];
#pragma unroll
    for (int s = 0; s < 6; ++s) {
        const int j = h * 6 + s;
        float acc = 0.f;
#pragma unroll
        for (int ii = 0; ii < 16; ++ii) acc += hv[ii] * w2[(size_t)(lane + 64 * ii) * 24 + j];
        lg[s] = wred(acc);
    }
    if (lane == 0) {
        const float temp = log1pf(expf(glt[h])) + 0.5f;
        float mx = -1e30f;
#pragma unroll
        for (int s = 0; s < 6; ++s) {
            lg[s] = (lg[s] + b2[h * 6 + s]) / temp;
            mx = fmaxf(mx, lg[s]);
        }
        float se = 0.f;
#pragma unroll
        for (int s = 0; s < 6; ++s) {
            lg[s] = expf(lg[s] - mx);
            se += lg[s];
        }
        float* o = &wts[(size_t)row * 24 + h * 6];
        const float inv = 1.f / se;
#pragma unroll
        for (int s = 0; s < 6; ++s) o[s] = lg[s] * inv;
    }
}

// -------------------------------------- fused = RMSNorm(sum ws*branch) * onorm_w (bf16 out)
__global__ __launch_bounds__(1024) void fuse_k(const float* __restrict__ f1,
                                               const float* __restrict__ f3,
                                               const float* __restrict__ f7,
                                               const float* __restrict__ f31,
                                               const float* __restrict__ dl,
                                               const float* __restrict__ vv,
                                               const float* __restrict__ wts,
                                               const float* __restrict__ onw,
                                               ushort_t* __restrict__ fused) {
    __shared__ float wloc[24];
    __shared__ float psum[16];
    const int row = blockIdx.x, t = threadIdx.x;
    if (t < 24) wloc[t] = wts[(size_t)row * 24 + t];
    __syncthreads();
    const int h = t >> 8, dd = t & 255;
    const size_t idx = (size_t)row * 1024 + t;
    const float* ptrs[6] = {f1, f3, f7, f31, dl, vv};
    float f = 0.f;
#pragma unroll
    for (int br = 0; br < 6; ++br) f += wloc[h * 6 + br] * ptrs[br][idx];
    float ss = wred(f * f);
    const int wave = t >> 6;
    if ((t & 63) == 0) psum[wave] = ss;
    __syncthreads();
    const float tot = psum[h * 4 + 0] + psum[h * 4 + 1] + psum[h * 4 + 2] + psum[h * 4 + 3];
    const float scale = rsqrtf(tot / 256.f + 1e-5f);
    fused[idx] = f2bs(f * scale * onw[dd]);
}

// ================================================================ launch
extern "C" void kernel_launch(void* const* d_in, const int* in_sizes, int n_in,
                              void* d_out, int out_size, void* d_ws, size_t ws_size,
                              hipStream_t stream) {
    const float* hs   = (const float*)d_in[0];
    const float* q_w  = (const float*)d_in[1];
    const float* k_w  = (const float*)d_in[2];
    const float* v_w  = (const float*)d_in[3];
    const float* b_w  = (const float*)d_in[4];
    const float* qc_w = (const float*)d_in[5];
    const float* kc_w = (const float*)d_in[6];
    const float* vc_w = (const float*)d_in[7];
    const float* f1w  = (const float*)d_in[8];
    const float* f3w  = (const float*)d_in[9];
    const float* f7w  = (const float*)d_in[10];
    const float* f31w = (const float*)d_in[11];
    const float* w1   = (const float*)d_in[12];
    const float* b1   = (const float*)d_in[13];
    const float* w2   = (const float*)d_in[14];
    const float* b2   = (const float*)d_in[15];
    const float* glt  = (const float*)d_in[16];
    const float* onw  = (const float*)d_in[17];
    const float* o_w  = (const float*)d_in[18];
    float* out = (float*)d_out;

    const size_t SZ = (size_t)B_ * L_ * D_;  // 4,194,304
    float* qlin = (float*)d_ws;       // -> fir1 later
    float* klin = qlin + SZ;          // -> fir3 later
    float* vlin = klin + SZ;          // -> fir7 later
    float* qbuf = vlin + SZ;          // -> hgate later
    float* kbuf = qbuf + SZ;          // -> fused_bf later
    float* vbuf = kbuf + SZ;
    float* f31b = vbuf + SZ;          // start: qwT/kwT/vwT live here (dead before conv31)
    float* wb   = f31b + SZ;          // after scan: gin_bf + w1T
    float* ub   = wb + SZ;            // after scan: owT
    float* dlt  = ub + SZ;            // start: hs_bf lives here (dead before scan)
    float* beta = dlt + SZ;
    float* attn = beta + (size_t)B_ * L_ * H_;
    float* stat = attn + (size_t)B_ * H_ * NC * 1024;
    float* wts  = stat + (size_t)B_ * L_ * H_ * 24;
    float* f1b = qlin;
    float* f3b = klin;
    float* f7b = vlin;
    float* hgate = qbuf;

    // bf16 aliases
    ushort_t* hs_bf = (ushort_t*)dlt;
    ushort_t* qwT = (ushort_t*)f31b;
    ushort_t* kwT = (ushort_t*)(f31b + 524288);
    ushort_t* vwT = (ushort_t*)(f31b + 1048576);
    ushort_t* gin_bf = (ushort_t*)wb;
    ushort_t* w1T = (ushort_t*)(wb + 2359296);
    ushort_t* owT = (ushort_t*)ub;
    ushort_t* fused_bf = (ushort_t*)kbuf;

    const int M = B_ * L_;  // 4096
    const dim3 gg(8, 32);   // N/128, M/128

    // weight transposes + activation cast
    tcast_k<<<dim3(32, 32), 256, 0, stream>>>(q_w, qwT, 1024, 1024);
    tcast_k<<<dim3(32, 32), 256, 0, stream>>>(k_w, kwT, 1024, 1024);
    tcast_k<<<dim3(32, 32), 256, 0, stream>>>(v_w, vwT, 1024, 1024);
    cast_k<<<4096, 256, 0, stream>>>(hs, hs_bf);
    // projections (bf16 MFMA)
    gemm_bf<0><<<gg, 256, 0, stream>>>(hs_bf, qwT, nullptr, qlin, M, 1024, 1024);
    gemm_bf<0><<<gg, 256, 0, stream>>>(hs_bf, kwT, nullptr, klin, M, 1024, 1024);
    gemm_bf<0><<<gg, 256, 0, stream>>>(hs_bf, vwT, nullptr, vlin, M, 1024, 1024);
    beta_k<<<M, 64, 0, stream>>>(hs, b_w, beta);
    // causal short conv + silu
    conv_k<4, 1><<<16384, 256, 0, stream>>>(qlin, qc_w, qbuf);
    conv_k<4, 1><<<16384, 256, 0, stream>>>(klin, kc_w, kbuf);
    conv_k<4, 1><<<16384, 256, 0, stream>>>(vlin, vc_w, vbuf);
    l2norm_k<<<M * H_, 64, 0, stream>>>(qbuf);
    l2norm_k<<<M * H_, 64, 0, stream>>>(kbuf);
    // chunkwise delta rule
    prep_k<<<B_ * H_ * NC, 256, 0, stream>>>(kbuf, vbuf, beta, wb, ub);
    attn_k<<<B_ * H_ * NC, 256, 0, stream>>>(qbuf, kbuf, attn);
    scan2_k<<<256, 256, 0, stream>>>(qbuf, kbuf, wb, ub, attn, dlt);
    // FIR branches on v
    conv_k<1, 0><<<16384, 256, 0, stream>>>(vbuf, f1w, f1b);
    conv_k<3, 0><<<16384, 256, 0, stream>>>(vbuf, f3w, f3b);
    conv_k<7, 0><<<16384, 256, 0, stream>>>(vbuf, f7w, f7b);
    conv_k<31, 0><<<16384, 256, 0, stream>>>(vbuf, f31w, f31b);
    // gate
    stats_k<<<M * H_, 64, 0, stream>>>(f1b, f3b, f7b, f31b, dlt, vbuf, stat);
    gatein_k<<<17920, 256, 0, stream>>>(hs, stat, gin_bf);
    tcast_k<<<dim3(32, 35), 256, 0, stream>>>(w1, w1T, 1120, 1024);
    gemm_bf<1><<<gg, 256, 0, stream>>>(gin_bf, w1T, b1, hgate, M, 1024, 1120);
    wts_k<<<M, 256, 0, stream>>>(hgate, w2, b2, glt, wts);
    fuse_k<<<M, 1024, 0, stream>>>(f1b, f3b, f7b, f31b, dlt, vbuf, wts, onw, fused_bf);
    // output projection
    tcast_k<<<dim3(32, 32), 256, 0, stream>>>(o_w, owT, 1024, 1024);
    gemm_bf<0><<<gg, 256, 0, stream>>>(fused_bf, owT, nullptr, out, M, 1024, 1024);
}

// Round 4
// 872.405 us; speedup vs baseline: 2.5600x; 1.4012x over previous
//
#include <hip/hip_runtime.h>
#include <hip/hip_bf16.h>
#include <math.h>

#define B_ 2
#define L_ 2048
#define D_ 1024
#define H_ 4
#define NC 64   // chunks per sequence

typedef unsigned short ushort_t;
typedef __bf16 bf16x8 __attribute__((ext_vector_type(8)));
typedef float f32x4 __attribute__((ext_vector_type(4)));

__device__ __forceinline__ ushort_t f2bs(float f) {
    __hip_bfloat16 h = __float2bfloat16(f);
    ushort_t u;
    __builtin_memcpy(&u, &h, 2);
    return u;
}
__device__ __forceinline__ float bs2f(ushort_t u) {
    unsigned int v = ((unsigned int)u) << 16;
    float f;
    __builtin_memcpy(&f, &v, 4);
    return f;
}

__device__ __forceinline__ float wred(float v) {
    v += __shfl_down(v, 32);
    v += __shfl_down(v, 16);
    v += __shfl_down(v, 8);
    v += __shfl_down(v, 4);
    v += __shfl_down(v, 2);
    v += __shfl_down(v, 1);
    return v;
}

__device__ __forceinline__ void gload16(const void* g, void* l) {
    __builtin_amdgcn_global_load_lds((const __attribute__((address_space(1))) void*)g,
                                     (__attribute__((address_space(3))) void*)l, 16, 0, 0);
}

// ------------------------------------------- transpose+cast: W[K][N] f32 -> WT[N][K] bf16
__global__ __launch_bounds__(256) void tcast_k(const float* __restrict__ W,
                                               ushort_t* __restrict__ WT, int K, int N) {
    __shared__ float tile[32 * 33];
    const int k0 = blockIdx.y << 5, n0 = blockIdx.x << 5;
    for (int e = threadIdx.x; e < 1024; e += 256)
        tile[(e >> 5) * 33 + (e & 31)] = W[(size_t)(k0 + (e >> 5)) * N + n0 + (e & 31)];
    __syncthreads();
    for (int e = threadIdx.x; e < 1024; e += 256)
        WT[(size_t)(n0 + (e >> 5)) * K + k0 + (e & 31)] = f2bs(tile[(e & 31) * 33 + (e >> 5)]);
}

// ------------------------------------------- cast f32 -> bf16 flat
__global__ __launch_bounds__(256) void cast_k(const float* __restrict__ x,
                                              ushort_t* __restrict__ y) {
    const int i = blockIdx.x * 256 + threadIdx.x;
    const float4 v = *(const float4*)&x[(size_t)i * 4];
    ushort4 p;
    p.x = f2bs(v.x); p.y = f2bs(v.y); p.z = f2bs(v.z); p.w = f2bs(v.w);
    *(ushort4*)&y[(size_t)i * 4] = p;
}

// ------------------------------------------- bf16 MFMA GEMM (TN): C = act(A @ Bt^T + bias)
template <int ACT>
__global__ __launch_bounds__(256) void gemm_bf(const ushort_t* __restrict__ A,
                                               const ushort_t* __restrict__ Bt,
                                               const float* __restrict__ bias,
                                               float* __restrict__ C,
                                               int M, int N, int K) {
    __shared__ ushort_t As[128 * 32];
    __shared__ ushort_t Bs[128 * 32];
    const int t = threadIdx.x;
    const int wv = t >> 6, l = t & 63;
    const int m0 = blockIdx.y << 7, n0 = blockIdx.x << 7;
    const int wm = wv & 1, wn = wv >> 1;
    const int q4 = l >> 4, c16 = l & 15;
    f32x4 acc[4][4];
#pragma unroll
    for (int i = 0; i < 4; ++i)
#pragma unroll
        for (int j = 0; j < 4; ++j) {
            f32x4 z = {0.f, 0.f, 0.f, 0.f};
            acc[i][j] = z;
        }
    const int srow = (l >> 2);
    const int scol = (l & 3) << 3;
    for (int k0 = 0; k0 < K; k0 += 32) {
        __syncthreads();
#pragma unroll
        for (int si = 0; si < 2; ++si) {
            const int s = wv * 2 + si;
            gload16(&A[(size_t)(m0 + s * 16 + srow) * K + k0 + scol], &As[s * 512]);
            gload16(&Bt[(size_t)(n0 + s * 16 + srow) * K + k0 + scol], &Bs[s * 512]);
        }
        __syncthreads();
        bf16x8 af[4], bff[4];
#pragma unroll
        for (int mi = 0; mi < 4; ++mi)
            af[mi] = *(const bf16x8*)&As[(wm * 64 + mi * 16 + c16) * 32 + q4 * 8];
#pragma unroll
        for (int ni = 0; ni < 4; ++ni)
            bff[ni] = *(const bf16x8*)&Bs[(wn * 64 + ni * 16 + c16) * 32 + q4 * 8];
#pragma unroll
        for (int mi = 0; mi < 4; ++mi)
#pragma unroll
            for (int ni = 0; ni < 4; ++ni)
                acc[mi][ni] = __builtin_amdgcn_mfma_f32_16x16x32_bf16(af[mi], bff[ni],
                                                                     acc[mi][ni], 0, 0, 0);
    }
#pragma unroll
    for (int mi = 0; mi < 4; ++mi)
#pragma unroll
        for (int ni = 0; ni < 4; ++ni)
#pragma unroll
            for (int r = 0; r < 4; ++r) {
                const int row = m0 + wm * 64 + mi * 16 + q4 * 4 + r;
                const int col = n0 + wn * 64 + ni * 16 + c16;
                float v = acc[mi][ni][r];
                if (ACT == 1) {
                    v += bias[col];
                    v = 0.5f * v * (1.0f + erff(v * 0.70710678118654752f));
                }
                C[(size_t)row * N + col] = v;
            }
}

// ------------------------------------------------- causal depthwise conv (+silu)
template <int KW, int SILU>
__global__ __launch_bounds__(256) void conv_k(const float* __restrict__ x,
                                              const float* __restrict__ w,
                                              float* __restrict__ y) {
    const int idx = blockIdx.x * 256 + threadIdx.x;
    const int c = idx & (D_ - 1);
    const int l = (idx >> 10) & (L_ - 1);
    float acc = 0.f;
#pragma unroll
    for (int tap = 0; tap < KW; ++tap) {
        const int off = tap - (KW - 1);
        if (l + off >= 0) acc += x[idx + off * D_] * w[c * KW + tap];
    }
    if (SILU) acc = acc / (1.f + expf(-acc));
    y[idx] = acc;
}

// -------------------------------------------------------------- beta = sigmoid(hs @ b_w)
__global__ __launch_bounds__(64) void beta_k(const float* __restrict__ hs,
                                             const float* __restrict__ bw,
                                             float* __restrict__ beta) {
    const int row = blockIdx.x;
    const int lane = threadIdx.x;
    float a0 = 0, a1 = 0, a2 = 0, a3 = 0;
    const float* hp = hs + (size_t)row * D_;
    for (int c = lane; c < D_; c += 64) {
        const float x = hp[c];
        a0 += x * bw[c * 4 + 0];
        a1 += x * bw[c * 4 + 1];
        a2 += x * bw[c * 4 + 2];
        a3 += x * bw[c * 4 + 3];
    }
    a0 = wred(a0); a1 = wred(a1); a2 = wred(a2); a3 = wred(a3);
    if (lane == 0) {
        float* o = beta + (size_t)row * 4;
        o[0] = 1.f / (1.f + expf(-a0));
        o[1] = 1.f / (1.f + expf(-a1));
        o[2] = 1.f / (1.f + expf(-a2));
        o[3] = 1.f / (1.f + expf(-a3));
    }
}

// ---------------------------------- l2norm rows of 256 (+ optional bf16 mirror)
__global__ __launch_bounds__(64) void l2norm_k(float* __restrict__ x,
                                               ushort_t* __restrict__ xbf) {
    const size_t base = (size_t)blockIdx.x * 256 + threadIdx.x * 4;
    float* p = x + base;
    float4 v = *(float4*)p;
    float ss = v.x * v.x + v.y * v.y + v.z * v.z + v.w * v.w;
    ss = wred(ss);
    ss = __shfl(ss, 0);
    const float s = rsqrtf(ss + 1e-6f);
    v.x *= s; v.y *= s; v.z *= s; v.w *= s;
    *(float4*)p = v;
    if (xbf) {
        ushort4 q;
        q.x = f2bs(v.x); q.y = f2bs(v.y); q.z = f2bs(v.z); q.w = f2bs(v.w);
        *(ushort4*)&xbf[base] = q;
    }
}

// ---------------------------------- per-chunk UT transform: T=(I-A)^-1, w=T@kb (bf16), u=T@(v*beta)
__global__ __launch_bounds__(256) void prep_k(const float* __restrict__ kg,
                                              const float* __restrict__ vg,
                                              const float* __restrict__ beta,
                                              ushort_t* __restrict__ wbf,
                                              float* __restrict__ ub) {
    __shared__ float lk[32 * 257];
    __shared__ float Am[32 * 33];
    __shared__ float Tm[32 * 33];
    __shared__ float lbeta[32];
    const int bid = blockIdx.x;  // B*H*NC
    const int bh = bid >> 6, ci = bid & 63;
    const int b = bh >> 2, h = bh & 3;
    const int t = threadIdx.x;
    const size_t gbase = ((size_t)(b * L_ + ci * 32)) * D_ + h * 256;
    for (int e = t; e < 8192; e += 256) {
        const int r = e >> 8, c = e & 255;
        lk[r * 257 + c] = kg[gbase + (size_t)r * D_ + c];
    }
    if (t < 32) lbeta[t] = beta[(size_t)(b * L_ + ci * 32 + t) * 4 + h];
    __syncthreads();
    for (int e = t; e < 1024; e += 256) {
        const int i = e >> 5, j = e & 31;
        float v = 0.f;
        if (j < i) {
            float d = 0.f;
            for (int c = 0; c < 256; ++c) d += lk[i * 257 + c] * lk[j * 257 + c];
            v = -lbeta[i] * d;
        }
        Am[i * 33 + j] = v;
        Tm[i * 33 + j] = (i == j) ? 1.f : 0.f;
    }
    __syncthreads();
    for (int i = 1; i < 32; ++i) {
        if (t < 32) {
            float s = 0.f;
            for (int j = 0; j < i; ++j) s += Am[i * 33 + j] * Tm[j * 33 + t];
            Tm[i * 33 + t] += s;
        }
        __syncthreads();
    }
    const size_t obase = (size_t)bid * 8192;
    for (int e = t; e < 8192; e += 256) {
        const int i = e >> 8, d = e & 255;
        float s = 0.f;
        for (int j = 0; j <= i; ++j) s += Tm[i * 33 + j] * lbeta[j] * lk[j * 257 + d];
        wbf[obase + e] = f2bs(s);
    }
    __syncthreads();
    for (int e = t; e < 8192; e += 256) {
        const int r = e >> 8, c = e & 255;
        lk[r * 257 + c] = vg[gbase + (size_t)r * D_ + c] * lbeta[r];
    }
    __syncthreads();
    for (int e = t; e < 8192; e += 256) {
        const int i = e >> 8, d = e & 255;
        float s = 0.f;
        for (int j = 0; j <= i; ++j) s += Tm[i * 33 + j] * lk[j * 257 + d];
        ub[obase + e] = s;
    }
}

// ------------------- attn = tril(q @ k^T) per chunk (bf16) + k^T chunk (bf16, [c][i])
__global__ __launch_bounds__(256) void attn_k(const float* __restrict__ qg,
                                              const float* __restrict__ kg,
                                              ushort_t* __restrict__ atg,
                                              ushort_t* __restrict__ ktg) {
    __shared__ float lk[32 * 257];
    const int bid = blockIdx.x;
    const int bh = bid >> 6, ci = bid & 63;
    const int b = bh >> 2, h = bh & 3;
    const int t = threadIdx.x;
    const size_t gbase = ((size_t)(b * L_ + ci * 32)) * D_ + h * 256;
    for (int e = t; e < 8192; e += 256) {
        const int r = e >> 8, c = e & 255;
        lk[r * 257 + c] = kg[gbase + (size_t)r * D_ + c];
    }
    __syncthreads();
    for (int e = t; e < 1024; e += 256) {
        const int i = e >> 5, j = e & 31;
        float v = 0.f;
        if (j <= i) {
            const float* qp = qg + gbase + (size_t)i * D_;
            for (int c = 0; c < 256; ++c) v += qp[c] * lk[j * 257 + c];
        }
        atg[(size_t)bid * 1024 + e] = f2bs(v);
    }
    // k^T: ktg[c][i] = k[i][c]
    for (int e = t; e < 8192; e += 256) {
        const int c = e >> 5, i = e & 31;
        ktg[(size_t)bid * 8192 + e] = f2bs(lk[i * 257 + c]);
    }
}

// ---------------------- MFMA sequential scan; dv tile = 16 (128 blocks)
// waves 0,1: uh = u - w@S (phase1) then o = q@S + attn@uh (phase2)
// waves 2,3: S += kT@uh via persistent AGPR accumulators; bf16 S mirror in LDS.
__global__ __launch_bounds__(256) void scan3_k(const ushort_t* __restrict__ qbf,
                                               const ushort_t* __restrict__ wbf,
                                               const float* __restrict__ ubuf,
                                               const ushort_t* __restrict__ atg,
                                               const ushort_t* __restrict__ ktg,
                                               float* __restrict__ dlt) {
    __shared__ ushort_t w_lds[32 * 256];   // rows 512B, seg-swizzled
    __shared__ ushort_t q_lds[32 * 256];
    __shared__ ushort_t kT_lds[256 * 32];  // rows 64B, seg-swizzled
    __shared__ ushort_t at_lds[32 * 32];
    __shared__ ushort_t uh_lds[16 * 40];   // [d][i], stride 40
    __shared__ ushort_t S_lds[16 * 264];   // [d][c] bf16 mirror of state
    const int t = threadIdx.x;
    const int wv = t >> 6, lane = t & 63;
    const int bh = blockIdx.x & 7, tile = blockIdx.x >> 3;
    const int b = bh >> 2, h = bh & 3;
    const int l16 = lane & 15, quad = lane >> 4;
    for (int e = t; e < 16 * 264; e += 256) S_lds[e] = 0;

    auto stage = [&](int ci) {
        const size_t cb = (size_t)(bh * NC + ci);
        const ushort_t* wsrc = wbf + cb * 8192;
        const ushort_t* ksrc = ktg + cb * 8192;
        const ushort_t* asrc = atg + cb * 1024;
        const ushort_t* qsrc = qbf + ((size_t)(b * L_ + ci * 32)) * 1024 + (h << 8);
#pragma unroll
        for (int j = 0; j < 4; ++j) {
            const int blk = (wv << 2) + j;
            {
                const int r = (blk << 1) + (lane >> 5);
                const int sg = (lane & 31) ^ (r & 31);
                gload16(wsrc + r * 256 + (sg << 3), &w_lds[blk << 9]);
                gload16(qsrc + r * 1024 + (sg << 3), &q_lds[blk << 9]);
            }
            {
                const int r = (blk << 4) + (lane >> 2);
                const int sg = (lane & 3) ^ ((r >> 1) & 3);
                gload16(ksrc + (r << 5) + (sg << 3), &kT_lds[blk << 9]);
            }
        }
        if (wv < 2) {
            const int r = (wv << 4) + (lane >> 2);
            const int sg = (lane & 3) ^ ((r >> 1) & 3);
            gload16(asrc + (r << 5) + (sg << 3), &at_lds[wv << 9]);
        }
    };
    auto afrag = [&](const ushort_t* bb, int it, int k0) -> bf16x8 {
        const int i = (it << 4) + l16;
        const int s = (k0 >> 3) + quad;
        return *(const bf16x8*)&bb[(i << 8) + ((s ^ i) << 3)];
    };
    auto sfrag = [&](int k0) -> bf16x8 {
        return *(const bf16x8*)&S_lds[l16 * 264 + k0 + (quad << 3)];
    };
    auto ktfrag = [&](int tc) -> bf16x8 {
        const int c = (tc << 4) + l16;
        const int s = quad ^ ((c >> 1) & 3);
        return *(const bf16x8*)&kT_lds[(c << 5) + (s << 3)];
    };
    auto atfrag = [&](int it) -> bf16x8 {
        const int i = (it << 4) + l16;
        const int s = quad ^ ((i >> 1) & 3);
        return *(const bf16x8*)&at_lds[(i << 5) + (s << 3)];
    };
    auto uhfrag = [&]() -> bf16x8 {
        return *(const bf16x8*)&uh_lds[l16 * 40 + (quad << 3)];
    };

    f32x4 Sacc[8];
#pragma unroll
    for (int j = 0; j < 8; ++j) {
        f32x4 z = {0.f, 0.f, 0.f, 0.f};
        Sacc[j] = z;
    }
    stage(0);
    __syncthreads();
    for (int ci = 0; ci < NC; ++ci) {
        const size_t cb = (size_t)(bh * NC + ci);
        const size_t gbase = ((size_t)(b * L_ + ci * 32)) * D_ + (h << 8);
        if (wv < 2) {
            float uv[4];
#pragma unroll
            for (int r = 0; r < 4; ++r)
                uv[r] = ubuf[cb * 8192 + (size_t)((wv << 4) + (quad << 2) + r) * 256 +
                             (tile << 4) + l16];
            f32x4 acc = {0.f, 0.f, 0.f, 0.f};
#pragma unroll
            for (int k0 = 0; k0 < 256; k0 += 32)
                acc = __builtin_amdgcn_mfma_f32_16x16x32_bf16(afrag(w_lds, wv, k0),
                                                              sfrag(k0), acc, 0, 0, 0);
            ushort4 up;
            up.x = f2bs(uv[0] - acc[0]);
            up.y = f2bs(uv[1] - acc[1]);
            up.z = f2bs(uv[2] - acc[2]);
            up.w = f2bs(uv[3] - acc[3]);
            *(ushort4*)&uh_lds[l16 * 40 + (wv << 4) + (quad << 2)] = up;
        }
        __syncthreads();  // B2: uh visible
        if (wv < 2) {
            f32x4 o = {0.f, 0.f, 0.f, 0.f};
#pragma unroll
            for (int k0 = 0; k0 < 256; k0 += 32)
                o = __builtin_amdgcn_mfma_f32_16x16x32_bf16(afrag(q_lds, wv, k0),
                                                            sfrag(k0), o, 0, 0, 0);
            o = __builtin_amdgcn_mfma_f32_16x16x32_bf16(atfrag(wv), uhfrag(), o, 0, 0, 0);
#pragma unroll
            for (int r = 0; r < 4; ++r)
                dlt[gbase + (size_t)((wv << 4) + (quad << 2) + r) * D_ + (tile << 4) + l16] =
                    o[r];
        } else {
            const int base_tc = (wv - 2) << 3;
            const bf16x8 uf = uhfrag();
#pragma unroll
            for (int j = 0; j < 8; ++j)
                Sacc[j] = __builtin_amdgcn_mfma_f32_16x16x32_bf16(ktfrag(base_tc + j), uf,
                                                                  Sacc[j], 0, 0, 0);
        }
        __syncthreads();  // B3: phase2 reads of S_lds done; staging consumed
        if (ci + 1 < NC) stage(ci + 1);
        if (wv >= 2) {
            const int base_tc = (wv - 2) << 3;
#pragma unroll
            for (int j = 0; j < 8; ++j) {
                const int c0 = ((base_tc + j) << 4) + (quad << 2);
#pragma unroll
                for (int r = 0; r < 4; ++r)
                    S_lds[l16 * 264 + c0 + r] = f2bs(Sacc[j][r]);
            }
        }
        __syncthreads();  // B4: S mirror + staging visible
    }
}

// -------------------------------------------------------------- branch stats
__global__ __launch_bounds__(64) void stats_k(const float* __restrict__ f1,
                                              const float* __restrict__ f3,
                                              const float* __restrict__ f7,
                                              const float* __restrict__ f31,
                                              const float* __restrict__ dl,
                                              const float* __restrict__ vv,
                                              float* __restrict__ stat) {
    const int row = blockIdx.x;
    const int lane = threadIdx.x;
    const float* ptrs[6] = {f1, f3, f7, f31, dl, vv};
    const size_t base = (size_t)row * 256;
    for (int br = 0; br < 6; ++br) {
        const float4 x = *(const float4*)&ptrs[br][base + lane * 4];
        float s1 = x.x + x.y + x.z + x.w;
        float s2 = x.x * x.x + x.y * x.y + x.z * x.z + x.w * x.w;
        float sa = fabsf(x.x) + fabsf(x.y) + fabsf(x.z) + fabsf(x.w);
        s1 = wred(s1); s2 = wred(s2); sa = wred(sa);
        if (lane == 0) {
            const float m = s1 / 256.f;
            float var = (s2 - 256.f * m * m) / 255.f;
            if (var < 0.f) var = 0.f;
            float* o = &stat[(size_t)row * 24 + br * 4];
            o[0] = m;
            o[1] = sqrtf(var);
            o[2] = sa / 256.f;
            o[3] = sqrtf(s2);
        }
    }
}

// -------------------------------------------------------------- gate_in = [hs, stats] (bf16)
__global__ __launch_bounds__(256) void gatein_k(const float* __restrict__ hs,
                                                const float* __restrict__ stat,
                                                ushort_t* __restrict__ gin) {
    const int idx = blockIdx.x * 256 + threadIdx.x;
    const int row = idx / 1120;
    const int j = idx - row * 1120;
    const float v = (j < 1024) ? hs[(size_t)row * 1024 + j]
                               : stat[(size_t)row * 96 + (j - 1024)];
    gin[idx] = f2bs(v);
}

// ---------------------------------------------- logits -> softmax weights
__global__ __launch_bounds__(256) void wts_k(const float* __restrict__ hg,
                                             const float* __restrict__ w2,
                                             const float* __restrict__ b2,
                                             const float* __restrict__ glt,
                                             float* __restrict__ wts) {
    const int row = blockIdx.x;
    const int h = threadIdx.x >> 6, lane = threadIdx.x & 63;
    float hv[16];
    const float* hp = hg + (size_t)row * 1024;
#pragma unroll
    for (int ii = 0; ii < 16; ++ii) hv[ii] = hp[lane + 64 * ii];
    float lg[6];
#pragma unroll
    for (int s = 0; s < 6; ++s) {
        const int j = h * 6 + s;
        float acc = 0.f;
#pragma unroll
        for (int ii = 0; ii < 16; ++ii) acc += hv[ii] * w2[(size_t)(lane + 64 * ii) * 24 + j];
        lg[s] = wred(acc);
    }
    if (lane == 0) {
        const float temp = log1pf(expf(glt[h])) + 0.5f;
        float mx = -1e30f;
#pragma unroll
        for (int s = 0; s < 6; ++s) {
            lg[s] = (lg[s] + b2[h * 6 + s]) / temp;
            mx = fmaxf(mx, lg[s]);
        }
        float se = 0.f;
#pragma unroll
        for (int s = 0; s < 6; ++s) {
            lg[s] = expf(lg[s] - mx);
            se += lg[s];
        }
        float* o = &wts[(size_t)row * 24 + h * 6];
        const float inv = 1.f / se;
#pragma unroll
        for (int s = 0; s < 6; ++s) o[s] = lg[s] * inv;
    }
}

// -------------------------------------- fused = RMSNorm(sum ws*branch) * onorm_w (bf16 out)
__global__ __launch_bounds__(1024) void fuse_k(const float* __restrict__ f1,
                                               const float* __restrict__ f3,
                                               const float* __restrict__ f7,
                                               const float* __restrict__ f31,
                                               const float* __restrict__ dl,
                                               const float* __restrict__ vv,
                                               const float* __restrict__ wts,
                                               const float* __restrict__ onw,
                                               ushort_t* __restrict__ fused) {
    __shared__ float wloc[24];
    __shared__ float psum[16];
    const int row = blockIdx.x, t = threadIdx.x;
    if (t < 24) wloc[t] = wts[(size_t)row * 24 + t];
    __syncthreads();
    const int h = t >> 8, dd = t & 255;
    const size_t idx = (size_t)row * 1024 + t;
    const float* ptrs[6] = {f1, f3, f7, f31, dl, vv};
    float f = 0.f;
#pragma unroll
    for (int br = 0; br < 6; ++br) f += wloc[h * 6 + br] * ptrs[br][idx];
    float ss = wred(f * f);
    const int wave = t >> 6;
    if ((t & 63) == 0) psum[wave] = ss;
    __syncthreads();
    const float tot = psum[h * 4 + 0] + psum[h * 4 + 1] + psum[h * 4 + 2] + psum[h * 4 + 3];
    const float scale = rsqrtf(tot / 256.f + 1e-5f);
    fused[idx] = f2bs(f * scale * onw[dd]);
}

// ================================================================ launch
extern "C" void kernel_launch(void* const* d_in, const int* in_sizes, int n_in,
                              void* d_out, int out_size, void* d_ws, size_t ws_size,
                              hipStream_t stream) {
    const float* hs   = (const float*)d_in[0];
    const float* q_w  = (const float*)d_in[1];
    const float* k_w  = (const float*)d_in[2];
    const float* v_w  = (const float*)d_in[3];
    const float* b_w  = (const float*)d_in[4];
    const float* qc_w = (const float*)d_in[5];
    const float* kc_w = (const float*)d_in[6];
    const float* vc_w = (const float*)d_in[7];
    const float* f1w  = (const float*)d_in[8];
    const float* f3w  = (const float*)d_in[9];
    const float* f7w  = (const float*)d_in[10];
    const float* f31w = (const float*)d_in[11];
    const float* w1   = (const float*)d_in[12];
    const float* b1   = (const float*)d_in[13];
    const float* w2   = (const float*)d_in[14];
    const float* b2   = (const float*)d_in[15];
    const float* glt  = (const float*)d_in[16];
    const float* onw  = (const float*)d_in[17];
    const float* o_w  = (const float*)d_in[18];
    float* out = (float*)d_out;

    const size_t SZ = (size_t)B_ * L_ * D_;  // 4,194,304
    float* qlin = (float*)d_ws;       // -> qbf (bf16) after conv; -> f1b after scan
    float* klin = qlin + SZ;          // -> ktg (bf16) after conv; -> f3b after scan
    float* vlin = klin + SZ;          // -> f7b after scan
    float* qbuf = vlin + SZ;          // -> hgate later
    float* kbuf = qbuf + SZ;          // -> fused_bf later
    float* vbuf = kbuf + SZ;
    float* f31b = vbuf + SZ;          // start: qwT/kwT/vwT (dead before conv31)
    float* wb   = f31b + SZ;          // wbf (bf16); after scan: gin_bf + w1T
    float* ub   = wb + SZ;            // u fp32; after scan: owT
    float* dlt  = ub + SZ;            // start: hs_bf (dead before scan)
    float* beta = dlt + SZ;
    float* attn = beta + (size_t)B_ * L_ * H_;  // at_bf (bf16, 1MB of 2MB region)
    float* stat = attn + (size_t)B_ * H_ * NC * 1024;
    float* wts  = stat + (size_t)B_ * L_ * H_ * 24;
    float* f1b = qlin;
    float* f3b = klin;
    float* f7b = vlin;
    float* hgate = qbuf;

    // bf16 aliases
    ushort_t* hs_bf = (ushort_t*)dlt;
    ushort_t* qwT = (ushort_t*)f31b;
    ushort_t* kwT = (ushort_t*)(f31b + 524288);
    ushort_t* vwT = (ushort_t*)(f31b + 1048576);
    ushort_t* gin_bf = (ushort_t*)wb;
    ushort_t* w1T = (ushort_t*)(wb + 2359296);
    ushort_t* owT = (ushort_t*)ub;
    ushort_t* fused_bf = (ushort_t*)kbuf;
    ushort_t* qbf = (ushort_t*)qlin;   // live [l2norm .. scan]
    ushort_t* ktg = (ushort_t*)klin;   // live [attn_k .. scan]
    ushort_t* wbf = (ushort_t*)wb;     // live [prep_k .. scan]
    ushort_t* at_bf = (ushort_t*)attn; // live [attn_k .. scan]

    const int M = B_ * L_;  // 4096
    const dim3 gg(8, 32);

    // weight transposes + activation cast
    tcast_k<<<dim3(32, 32), 256, 0, stream>>>(q_w, qwT, 1024, 1024);
    tcast_k<<<dim3(32, 32), 256, 0, stream>>>(k_w, kwT, 1024, 1024);
    tcast_k<<<dim3(32, 32), 256, 0, stream>>>(v_w, vwT, 1024, 1024);
    cast_k<<<4096, 256, 0, stream>>>(hs, hs_bf);
    // projections (bf16 MFMA)
    gemm_bf<0><<<gg, 256, 0, stream>>>(hs_bf, qwT, nullptr, qlin, M, 1024, 1024);
    gemm_bf<0><<<gg, 256, 0, stream>>>(hs_bf, kwT, nullptr, klin, M, 1024, 1024);
    gemm_bf<0><<<gg, 256, 0, stream>>>(hs_bf, vwT, nullptr, vlin, M, 1024, 1024);
    beta_k<<<M, 64, 0, stream>>>(hs, b_w, beta);
    // causal short conv + silu
    conv_k<4, 1><<<16384, 256, 0, stream>>>(qlin, qc_w, qbuf);
    conv_k<4, 1><<<16384, 256, 0, stream>>>(klin, kc_w, kbuf);
    conv_k<4, 1><<<16384, 256, 0, stream>>>(vlin, vc_w, vbuf);
    l2norm_k<<<M * H_, 64, 0, stream>>>(qbuf, qbf);
    l2norm_k<<<M * H_, 64, 0, stream>>>(kbuf, (ushort_t*)nullptr);
    // chunkwise delta rule
    prep_k<<<B_ * H_ * NC, 256, 0, stream>>>(kbuf, vbuf, beta, wbf, ub);
    attn_k<<<B_ * H_ * NC, 256, 0, stream>>>(qbuf, kbuf, at_bf, ktg);
    scan3_k<<<128, 256, 0, stream>>>(qbf, wbf, ub, at_bf, ktg, dlt);
    // FIR branches on v
    conv_k<1, 0><<<16384, 256, 0, stream>>>(vbuf, f1w, f1b);
    conv_k<3, 0><<<16384, 256, 0, stream>>>(vbuf, f3w, f3b);
    conv_k<7, 0><<<16384, 256, 0, stream>>>(vbuf, f7w, f7b);
    conv_k<31, 0><<<16384, 256, 0, stream>>>(vbuf, f31w, f31b);
    // gate
    stats_k<<<M * H_, 64, 0, stream>>>(f1b, f3b, f7b, f31b, dlt, vbuf, stat);
    gatein_k<<<17920, 256, 0, stream>>>(hs, stat, gin_bf);
    tcast_k<<<dim3(32, 35), 256, 0, stream>>>(w1, w1T, 1120, 1024);
    gemm_bf<1><<<gg, 256, 0, stream>>>(gin_bf, w1T, b1, hgate, M, 1024, 1120);
    wts_k<<<M, 256, 0, stream>>>(hgate, w2, b2, glt, wts);
    fuse_k<<<M, 1024, 0, stream>>>(f1b, f3b, f7b, f31b, dlt, vbuf, wts, onw, fused_bf);
    // output projection
    tcast_k<<<dim3(32, 32), 256, 0, stream>>>(o_w, owT, 1024, 1024);
    gemm_bf<0><<<gg, 256, 0, stream>>>(fused_bf, owT, nullptr, out, M, 1024, 1024);
}

// Round 5
// 636.136 us; speedup vs baseline: 3.5109x; 1.3714x over previous
//
#include <hip/hip_runtime.h>
#include <hip/hip_bf16.h>
#include <math.h>

#define B_ 2
#define L_ 2048
#define D_ 1024
#define H_ 4
#define NC 64   // chunks per sequence

typedef unsigned short ushort_t;
typedef __bf16 bf16x8 __attribute__((ext_vector_type(8)));
typedef float f32x4 __attribute__((ext_vector_type(4)));

__device__ __forceinline__ ushort_t f2bs(float f) {
    __hip_bfloat16 h = __float2bfloat16(f);
    ushort_t u;
    __builtin_memcpy(&u, &h, 2);
    return u;
}

__device__ __forceinline__ float wred(float v) {
    v += __shfl_down(v, 32);
    v += __shfl_down(v, 16);
    v += __shfl_down(v, 8);
    v += __shfl_down(v, 4);
    v += __shfl_down(v, 2);
    v += __shfl_down(v, 1);
    return v;
}

__device__ __forceinline__ void gload16(const void* g, void* l) {
    __builtin_amdgcn_global_load_lds((const __attribute__((address_space(1))) void*)g,
                                     (__attribute__((address_space(3))) void*)l, 16, 0, 0);
}

// ------------------------------------------- transpose+cast: W[K][N] f32 -> WT[N][K] bf16
__global__ __launch_bounds__(256) void tcast_k(const float* __restrict__ W,
                                               ushort_t* __restrict__ WT, int K, int N) {
    __shared__ float tile[32 * 33];
    const int k0 = blockIdx.y << 5, n0 = blockIdx.x << 5;
    for (int e = threadIdx.x; e < 1024; e += 256)
        tile[(e >> 5) * 33 + (e & 31)] = W[(size_t)(k0 + (e >> 5)) * N + n0 + (e & 31)];
    __syncthreads();
    for (int e = threadIdx.x; e < 1024; e += 256)
        WT[(size_t)(n0 + (e >> 5)) * K + k0 + (e & 31)] = f2bs(tile[(e & 31) * 33 + (e >> 5)]);
}

// ------------------------------------------- cast f32 -> bf16 flat
__global__ __launch_bounds__(256) void cast_k(const float* __restrict__ x,
                                              ushort_t* __restrict__ y) {
    const int i = blockIdx.x * 256 + threadIdx.x;
    const float4 v = *(const float4*)&x[(size_t)i * 4];
    ushort4 p;
    p.x = f2bs(v.x); p.y = f2bs(v.y); p.z = f2bs(v.z); p.w = f2bs(v.w);
    *(ushort4*)&y[(size_t)i * 4] = p;
}

// ------------------------------------------- bf16 MFMA GEMM (TN): C = act(A @ Bt^T + bias)
template <int ACT>
__global__ __launch_bounds__(256) void gemm_bf(const ushort_t* __restrict__ A,
                                               const ushort_t* __restrict__ Bt,
                                               const float* __restrict__ bias,
                                               float* __restrict__ C,
                                               int M, int N, int K) {
    __shared__ ushort_t As[128 * 32];
    __shared__ ushort_t Bs[128 * 32];
    const int t = threadIdx.x;
    const int wv = t >> 6, l = t & 63;
    const int m0 = blockIdx.y << 7, n0 = blockIdx.x << 7;
    const int wm = wv & 1, wn = wv >> 1;
    const int q4 = l >> 4, c16 = l & 15;
    f32x4 acc[4][4];
#pragma unroll
    for (int i = 0; i < 4; ++i)
#pragma unroll
        for (int j = 0; j < 4; ++j) {
            f32x4 z = {0.f, 0.f, 0.f, 0.f};
            acc[i][j] = z;
        }
    const int srow = (l >> 2);
    const int scol = (l & 3) << 3;
    for (int k0 = 0; k0 < K; k0 += 32) {
        __syncthreads();
#pragma unroll
        for (int si = 0; si < 2; ++si) {
            const int s = wv * 2 + si;
            gload16(&A[(size_t)(m0 + s * 16 + srow) * K + k0 + scol], &As[s * 512]);
            gload16(&Bt[(size_t)(n0 + s * 16 + srow) * K + k0 + scol], &Bs[s * 512]);
        }
        __syncthreads();
        bf16x8 af[4], bff[4];
#pragma unroll
        for (int mi = 0; mi < 4; ++mi)
            af[mi] = *(const bf16x8*)&As[(wm * 64 + mi * 16 + c16) * 32 + q4 * 8];
#pragma unroll
        for (int ni = 0; ni < 4; ++ni)
            bff[ni] = *(const bf16x8*)&Bs[(wn * 64 + ni * 16 + c16) * 32 + q4 * 8];
#pragma unroll
        for (int mi = 0; mi < 4; ++mi)
#pragma unroll
            for (int ni = 0; ni < 4; ++ni)
                acc[mi][ni] = __builtin_amdgcn_mfma_f32_16x16x32_bf16(af[mi], bff[ni],
                                                                     acc[mi][ni], 0, 0, 0);
    }
#pragma unroll
    for (int mi = 0; mi < 4; ++mi)
#pragma unroll
        for (int ni = 0; ni < 4; ++ni)
#pragma unroll
            for (int r = 0; r < 4; ++r) {
                const int row = m0 + wm * 64 + mi * 16 + q4 * 4 + r;
                const int col = n0 + wn * 64 + ni * 16 + c16;
                float v = acc[mi][ni][r];
                if (ACT == 1) {
                    v += bias[col];
                    v = 0.5f * v * (1.0f + erff(v * 0.70710678118654752f));
                }
                C[(size_t)row * N + col] = v;
            }
}

// ---------------- fused causal conv(K=4) + silu (+ row l2norm, + bf16 mirror), LDS-tiled
// X row stride 3072 (qkv fused buffer); one block = (b, 32 l-rows, head)
template <int DO_NORM, int EMIT_BF>
__global__ __launch_bounds__(256) void convql_k(const float* __restrict__ X,
                                                const float* __restrict__ cw,
                                                float* __restrict__ Y,
                                                ushort_t* __restrict__ Ybf) {
    __shared__ float xs[35 * 256];
    const int bid = blockIdx.x;
    const int h = bid & 3, lt = (bid >> 2) & 63, b = bid >> 8;
    const int t = threadIdx.x;
    const int l0 = lt << 5;
    const int cg = (h << 8) | t;
    for (int e = t; e < 35 * 256; e += 256) {
        const int r = e >> 8, c = e & 255;
        const int gl = l0 + r - 3;
        xs[e] = (gl >= 0) ? X[((size_t)(b * L_) + gl) * 3072 + (h << 8) + c] : 0.f;
    }
    const float w0 = cw[cg * 4 + 0], w1 = cw[cg * 4 + 1];
    const float w2 = cw[cg * 4 + 2], w3 = cw[cg * 4 + 3];
    __syncthreads();
    float yr[32];
#pragma unroll
    for (int l = 0; l < 32; ++l) {
        const float a = xs[(l + 0) * 256 + t] * w0 + xs[(l + 1) * 256 + t] * w1 +
                        xs[(l + 2) * 256 + t] * w2 + xs[(l + 3) * 256 + t] * w3;
        yr[l] = a / (1.f + expf(-a));
    }
    if (DO_NORM) {
        __syncthreads();  // xs reads done
#pragma unroll
        for (int l = 0; l < 32; ++l) xs[l * 256 + t] = yr[l];
        __syncthreads();
        const int wv = t >> 6, lane = t & 63;
#pragma unroll
        for (int ri = 0; ri < 8; ++ri) {
            const int r = wv * 8 + ri;
            float4 v = *(float4*)&xs[r * 256 + lane * 4];
            float ss = v.x * v.x + v.y * v.y + v.z * v.z + v.w * v.w;
            ss = wred(ss);
            ss = __shfl(ss, 0);
            const float s = rsqrtf(ss + 1e-6f);
            v.x *= s; v.y *= s; v.z *= s; v.w *= s;
            const size_t go = ((size_t)(b * L_) + l0 + r) * 1024 + (h << 8) + lane * 4;
            *(float4*)&Y[go] = v;
            if (EMIT_BF) {
                ushort4 p;
                p.x = f2bs(v.x); p.y = f2bs(v.y); p.z = f2bs(v.z); p.w = f2bs(v.w);
                *(ushort4*)&Ybf[go] = p;
            }
        }
    } else {
#pragma unroll
        for (int l = 0; l < 32; ++l)
            Y[((size_t)(b * L_) + l0 + l) * 1024 + cg] = yr[l];
    }
}

// ---------------- fused FIR branches (K=1,3,7,31), LDS-tiled, one read of v
__global__ __launch_bounds__(256) void fir_k(const float* __restrict__ V,
                                             const float* __restrict__ w1w,
                                             const float* __restrict__ w3w,
                                             const float* __restrict__ w7w,
                                             const float* __restrict__ w31w,
                                             float* __restrict__ o1,
                                             float* __restrict__ o3,
                                             float* __restrict__ o7,
                                             float* __restrict__ o31) {
    __shared__ float xs[62 * 256];
    const int bid = blockIdx.x;
    const int h = bid & 3, lt = (bid >> 2) & 63, b = bid >> 8;
    const int t = threadIdx.x;
    const int l0 = lt << 5;
    const int cg = (h << 8) | t;
    for (int e = t; e < 62 * 256; e += 256) {
        const int r = e >> 8, c = e & 255;
        const int gl = l0 + r - 30;
        xs[e] = (gl >= 0) ? V[((size_t)(b * L_) + gl) * 1024 + (h << 8) + c] : 0.f;
    }
    float lw31[31], lw7[7], lw3[3];
#pragma unroll
    for (int j = 0; j < 31; ++j) lw31[j] = w31w[cg * 31 + j];
#pragma unroll
    for (int j = 0; j < 7; ++j) lw7[j] = w7w[cg * 7 + j];
#pragma unroll
    for (int j = 0; j < 3; ++j) lw3[j] = w3w[cg * 3 + j];
    const float lw1 = w1w[cg];
    __syncthreads();
    for (int l = 0; l < 32; ++l) {
        float a31 = 0.f, a7 = 0.f, a3 = 0.f, v = 0.f;
#pragma unroll
        for (int j = 0; j < 31; ++j) {
            v = xs[(l + j) * 256 + t];
            a31 += v * lw31[j];
            if (j >= 24) a7 += v * lw7[j - 24];
            if (j >= 28) a3 += v * lw3[j - 28];
        }
        const size_t go = ((size_t)(b * L_) + l0 + l) * 1024 + cg;
        o31[go] = a31;
        o7[go] = a7;
        o3[go] = a3;
        o1[go] = v * lw1;
    }
}

// -------------------------------------------------------------- beta = sigmoid(hs @ b_w)
__global__ __launch_bounds__(64) void beta_k(const float* __restrict__ hs,
                                             const float* __restrict__ bw,
                                             float* __restrict__ beta) {
    const int row = blockIdx.x;
    const int lane = threadIdx.x;
    float a0 = 0, a1 = 0, a2 = 0, a3 = 0;
    const float* hp = hs + (size_t)row * D_;
    for (int c = lane; c < D_; c += 64) {
        const float x = hp[c];
        a0 += x * bw[c * 4 + 0];
        a1 += x * bw[c * 4 + 1];
        a2 += x * bw[c * 4 + 2];
        a3 += x * bw[c * 4 + 3];
    }
    a0 = wred(a0); a1 = wred(a1); a2 = wred(a2); a3 = wred(a3);
    if (lane == 0) {
        float* o = beta + (size_t)row * 4;
        o[0] = 1.f / (1.f + expf(-a0));
        o[1] = 1.f / (1.f + expf(-a1));
        o[2] = 1.f / (1.f + expf(-a2));
        o[3] = 1.f / (1.f + expf(-a3));
    }
}

// ---------------------------------- per-chunk UT transform: T=(I-A)^-1, w=T@kb (bf16), u=T@(v*beta)
__global__ __launch_bounds__(256) void prep_k(const float* __restrict__ kg,
                                              const float* __restrict__ vg,
                                              const float* __restrict__ beta,
                                              ushort_t* __restrict__ wbf,
                                              float* __restrict__ ub) {
    __shared__ float lk[32 * 257];
    __shared__ float Am[32 * 33];
    __shared__ float Tm[32 * 33];
    __shared__ float lbeta[32];
    const int bid = blockIdx.x;  // B*H*NC
    const int bh = bid >> 6, ci = bid & 63;
    const int b = bh >> 2, h = bh & 3;
    const int t = threadIdx.x;
    const size_t gbase = ((size_t)(b * L_ + ci * 32)) * D_ + h * 256;
    for (int e = t; e < 8192; e += 256) {
        const int r = e >> 8, c = e & 255;
        lk[r * 257 + c] = kg[gbase + (size_t)r * D_ + c];
    }
    if (t < 32) lbeta[t] = beta[(size_t)(b * L_ + ci * 32 + t) * 4 + h];
    __syncthreads();
    for (int e = t; e < 1024; e += 256) {
        const int i = e >> 5, j = e & 31;
        float v = 0.f;
        if (j < i) {
            float d = 0.f;
            for (int c = 0; c < 256; ++c) d += lk[i * 257 + c] * lk[j * 257 + c];
            v = -lbeta[i] * d;
        }
        Am[i * 33 + j] = v;
        Tm[i * 33 + j] = (i == j) ? 1.f : 0.f;
    }
    __syncthreads();
    for (int i = 1; i < 32; ++i) {
        if (t < 32) {
            float s = 0.f;
            for (int j = 0; j < i; ++j) s += Am[i * 33 + j] * Tm[j * 33 + t];
            Tm[i * 33 + t] += s;
        }
        __syncthreads();
    }
    const size_t obase = (size_t)bid * 8192;
    for (int e = t; e < 8192; e += 256) {
        const int i = e >> 8, d = e & 255;
        float s = 0.f;
        for (int j = 0; j <= i; ++j) s += Tm[i * 33 + j] * lbeta[j] * lk[j * 257 + d];
        wbf[obase + e] = f2bs(s);
    }
    __syncthreads();
    for (int e = t; e < 8192; e += 256) {
        const int r = e >> 8, c = e & 255;
        lk[r * 257 + c] = vg[gbase + (size_t)r * D_ + c] * lbeta[r];
    }
    __syncthreads();
    for (int e = t; e < 8192; e += 256) {
        const int i = e >> 8, d = e & 255;
        float s = 0.f;
        for (int j = 0; j <= i; ++j) s += Tm[i * 33 + j] * lk[j * 257 + d];
        ub[obase + e] = s;
    }
}

// ------------------- attn = tril(q @ k^T) per chunk (bf16) + k^T chunk (bf16, [c][i])
__global__ __launch_bounds__(256) void attn_k(const float* __restrict__ qg,
                                              const float* __restrict__ kg,
                                              ushort_t* __restrict__ atg,
                                              ushort_t* __restrict__ ktg) {
    __shared__ float lk[32 * 257];
    const int bid = blockIdx.x;
    const int bh = bid >> 6, ci = bid & 63;
    const int b = bh >> 2, h = bh & 3;
    const int t = threadIdx.x;
    const size_t gbase = ((size_t)(b * L_ + ci * 32)) * D_ + h * 256;
    for (int e = t; e < 8192; e += 256) {
        const int r = e >> 8, c = e & 255;
        lk[r * 257 + c] = kg[gbase + (size_t)r * D_ + c];
    }
    __syncthreads();
    for (int e = t; e < 1024; e += 256) {
        const int i = e >> 5, j = e & 31;
        float v = 0.f;
        if (j <= i) {
            const float* qp = qg + gbase + (size_t)i * D_;
            for (int c = 0; c < 256; ++c) v += qp[c] * lk[j * 257 + c];
        }
        atg[(size_t)bid * 1024 + e] = f2bs(v);
    }
    for (int e = t; e < 8192; e += 256) {
        const int c = e >> 5, i = e & 31;
        ktg[(size_t)bid * 8192 + e] = f2bs(lk[i * 257 + c]);
    }
}

// ---------------------- MFMA sequential scan; dv tile = 16 (128 blocks)
__global__ __launch_bounds__(256) void scan3_k(const ushort_t* __restrict__ qbf,
                                               const ushort_t* __restrict__ wbf,
                                               const float* __restrict__ ubuf,
                                               const ushort_t* __restrict__ atg,
                                               const ushort_t* __restrict__ ktg,
                                               float* __restrict__ dlt) {
    __shared__ ushort_t w_lds[32 * 256];
    __shared__ ushort_t q_lds[32 * 256];
    __shared__ ushort_t kT_lds[256 * 32];
    __shared__ ushort_t at_lds[32 * 32];
    __shared__ ushort_t uh_lds[16 * 40];
    __shared__ ushort_t S_lds[16 * 264];
    const int t = threadIdx.x;
    const int wv = t >> 6, lane = t & 63;
    const int bh = blockIdx.x & 7, tile = blockIdx.x >> 3;
    const int b = bh >> 2, h = bh & 3;
    const int l16 = lane & 15, quad = lane >> 4;
    for (int e = t; e < 16 * 264; e += 256) S_lds[e] = 0;

    auto stage = [&](int ci) {
        const size_t cb = (size_t)(bh * NC + ci);
        const ushort_t* wsrc = wbf + cb * 8192;
        const ushort_t* ksrc = ktg + cb * 8192;
        const ushort_t* asrc = atg + cb * 1024;
        const ushort_t* qsrc = qbf + ((size_t)(b * L_ + ci * 32)) * 1024 + (h << 8);
#pragma unroll
        for (int j = 0; j < 4; ++j) {
            const int blk = (wv << 2) + j;
            {
                const int r = (blk << 1) + (lane >> 5);
                const int sg = (lane & 31) ^ (r & 31);
                gload16(wsrc + r * 256 + (sg << 3), &w_lds[blk << 9]);
                gload16(qsrc + r * 1024 + (sg << 3), &q_lds[blk << 9]);
            }
            {
                const int r = (blk << 4) + (lane >> 2);
                const int sg = (lane & 3) ^ ((r >> 1) & 3);
                gload16(ksrc + (r << 5) + (sg << 3), &kT_lds[blk << 9]);
            }
        }
        if (wv < 2) {
            const int r = (wv << 4) + (lane >> 2);
            const int sg = (lane & 3) ^ ((r >> 1) & 3);
            gload16(asrc + (r << 5) + (sg << 3), &at_lds[wv << 9]);
        }
    };
    auto afrag = [&](const ushort_t* bb, int it, int k0) -> bf16x8 {
        const int i = (it << 4) + l16;
        const int s = (k0 >> 3) + quad;
        return *(const bf16x8*)&bb[(i << 8) + ((s ^ i) << 3)];
    };
    auto sfrag = [&](int k0) -> bf16x8 {
        return *(const bf16x8*)&S_lds[l16 * 264 + k0 + (quad << 3)];
    };
    auto ktfrag = [&](int tc) -> bf16x8 {
        const int c = (tc << 4) + l16;
        const int s = quad ^ ((c >> 1) & 3);
        return *(const bf16x8*)&kT_lds[(c << 5) + (s << 3)];
    };
    auto atfrag = [&](int it) -> bf16x8 {
        const int i = (it << 4) + l16;
        const int s = quad ^ ((i >> 1) & 3);
        return *(const bf16x8*)&at_lds[(i << 5) + (s << 3)];
    };
    auto uhfrag = [&]() -> bf16x8 {
        return *(const bf16x8*)&uh_lds[l16 * 40 + (quad << 3)];
    };

    f32x4 Sacc[8];
#pragma unroll
    for (int j = 0; j < 8; ++j) {
        f32x4 z = {0.f, 0.f, 0.f, 0.f};
        Sacc[j] = z;
    }
    stage(0);
    __syncthreads();
    for (int ci = 0; ci < NC; ++ci) {
        const size_t cb = (size_t)(bh * NC + ci);
        const size_t gbase = ((size_t)(b * L_ + ci * 32)) * D_ + (h << 8);
        if (wv < 2) {
            float uv[4];
#pragma unroll
            for (int r = 0; r < 4; ++r)
                uv[r] = ubuf[cb * 8192 + (size_t)((wv << 4) + (quad << 2) + r) * 256 +
                             (tile << 4) + l16];
            f32x4 acc = {0.f, 0.f, 0.f, 0.f};
#pragma unroll
            for (int k0 = 0; k0 < 256; k0 += 32)
                acc = __builtin_amdgcn_mfma_f32_16x16x32_bf16(afrag(w_lds, wv, k0),
                                                              sfrag(k0), acc, 0, 0, 0);
            ushort4 up;
            up.x = f2bs(uv[0] - acc[0]);
            up.y = f2bs(uv[1] - acc[1]);
            up.z = f2bs(uv[2] - acc[2]);
            up.w = f2bs(uv[3] - acc[3]);
            *(ushort4*)&uh_lds[l16 * 40 + (wv << 4) + (quad << 2)] = up;
        }
        __syncthreads();
        if (wv < 2) {
            f32x4 o = {0.f, 0.f, 0.f, 0.f};
#pragma unroll
            for (int k0 = 0; k0 < 256; k0 += 32)
                o = __builtin_amdgcn_mfma_f32_16x16x32_bf16(afrag(q_lds, wv, k0),
                                                            sfrag(k0), o, 0, 0, 0);
            o = __builtin_amdgcn_mfma_f32_16x16x32_bf16(atfrag(wv), uhfrag(), o, 0, 0, 0);
#pragma unroll
            for (int r = 0; r < 4; ++r)
                dlt[gbase + (size_t)((wv << 4) + (quad << 2) + r) * D_ + (tile << 4) + l16] =
                    o[r];
        } else {
            const int base_tc = (wv - 2) << 3;
            const bf16x8 uf = uhfrag();
#pragma unroll
            for (int j = 0; j < 8; ++j)
                Sacc[j] = __builtin_amdgcn_mfma_f32_16x16x32_bf16(ktfrag(base_tc + j), uf,
                                                                  Sacc[j], 0, 0, 0);
        }
        __syncthreads();
        if (ci + 1 < NC) stage(ci + 1);
        if (wv >= 2) {
            const int base_tc = (wv - 2) << 3;
#pragma unroll
            for (int j = 0; j < 8; ++j) {
                const int c0 = ((base_tc + j) << 4) + (quad << 2);
#pragma unroll
                for (int r = 0; r < 4; ++r)
                    S_lds[l16 * 264 + c0 + r] = f2bs(Sacc[j][r]);
            }
        }
        __syncthreads();
    }
}

// -------------------------------------------------------------- branch stats
__global__ __launch_bounds__(64) void stats_k(const float* __restrict__ f1,
                                              const float* __restrict__ f3,
                                              const float* __restrict__ f7,
                                              const float* __restrict__ f31,
                                              const float* __restrict__ dl,
                                              const float* __restrict__ vv,
                                              float* __restrict__ stat) {
    const int row = blockIdx.x;
    const int lane = threadIdx.x;
    const float* ptrs[6] = {f1, f3, f7, f31, dl, vv};
    const size_t base = (size_t)row * 256;
    for (int br = 0; br < 6; ++br) {
        const float4 x = *(const float4*)&ptrs[br][base + lane * 4];
        float s1 = x.x + x.y + x.z + x.w;
        float s2 = x.x * x.x + x.y * x.y + x.z * x.z + x.w * x.w;
        float sa = fabsf(x.x) + fabsf(x.y) + fabsf(x.z) + fabsf(x.w);
        s1 = wred(s1); s2 = wred(s2); sa = wred(sa);
        if (lane == 0) {
            const float m = s1 / 256.f;
            float var = (s2 - 256.f * m * m) / 255.f;
            if (var < 0.f) var = 0.f;
            float* o = &stat[(size_t)row * 24 + br * 4];
            o[0] = m;
            o[1] = sqrtf(var);
            o[2] = sa / 256.f;
            o[3] = sqrtf(s2);
        }
    }
}

// -------------------------------------------------------------- gate_in = [hs, stats] (bf16)
__global__ __launch_bounds__(256) void gatein_k(const float* __restrict__ hs,
                                                const float* __restrict__ stat,
                                                ushort_t* __restrict__ gin) {
    const int idx = blockIdx.x * 256 + threadIdx.x;
    const int row = idx / 1120;
    const int j = idx - row * 1120;
    const float v = (j < 1024) ? hs[(size_t)row * 1024 + j]
                               : stat[(size_t)row * 96 + (j - 1024)];
    gin[idx] = f2bs(v);
}

// ---------------------------------------------- logits -> softmax weights
__global__ __launch_bounds__(256) void wts_k(const float* __restrict__ hg,
                                             const float* __restrict__ w2,
                                             const float* __restrict__ b2,
                                             const float* __restrict__ glt,
                                             float* __restrict__ wts) {
    const int row = blockIdx.x;
    const int h = threadIdx.x >> 6, lane = threadIdx.x & 63;
    float hv[16];
    const float* hp = hg + (size_t)row * 1024;
#pragma unroll
    for (int ii = 0; ii < 16; ++ii) hv[ii] = hp[lane + 64 * ii];
    float lg[6];
#pragma unroll
    for (int s = 0; s < 6; ++s) {
        const int j = h * 6 + s;
        float acc = 0.f;
#pragma unroll
        for (int ii = 0; ii < 16; ++ii) acc += hv[ii] * w2[(size_t)(lane + 64 * ii) * 24 + j];
        lg[s] = wred(acc);
    }
    if (lane == 0) {
        const float temp = log1pf(expf(glt[h])) + 0.5f;
        float mx = -1e30f;
#pragma unroll
        for (int s = 0; s < 6; ++s) {
            lg[s] = (lg[s] + b2[h * 6 + s]) / temp;
            mx = fmaxf(mx, lg[s]);
        }
        float se = 0.f;
#pragma unroll
        for (int s = 0; s < 6; ++s) {
            lg[s] = expf(lg[s] - mx);
            se += lg[s];
        }
        float* o = &wts[(size_t)row * 24 + h * 6];
        const float inv = 1.f / se;
#pragma unroll
        for (int s = 0; s < 6; ++s) o[s] = lg[s] * inv;
    }
}

// -------------------------------------- fused = RMSNorm(sum ws*branch) * onorm_w (bf16 out)
__global__ __launch_bounds__(1024) void fuse_k(const float* __restrict__ f1,
                                               const float* __restrict__ f3,
                                               const float* __restrict__ f7,
                                               const float* __restrict__ f31,
                                               const float* __restrict__ dl,
                                               const float* __restrict__ vv,
                                               const float* __restrict__ wts,
                                               const float* __restrict__ onw,
                                               ushort_t* __restrict__ fused) {
    __shared__ float wloc[24];
    __shared__ float psum[16];
    const int row = blockIdx.x, t = threadIdx.x;
    if (t < 24) wloc[t] = wts[(size_t)row * 24 + t];
    __syncthreads();
    const int h = t >> 8, dd = t & 255;
    const size_t idx = (size_t)row * 1024 + t;
    const float* ptrs[6] = {f1, f3, f7, f31, dl, vv};
    float f = 0.f;
#pragma unroll
    for (int br = 0; br < 6; ++br) f += wloc[h * 6 + br] * ptrs[br][idx];
    float ss = wred(f * f);
    const int wave = t >> 6;
    if ((t & 63) == 0) psum[wave] = ss;
    __syncthreads();
    const float tot = psum[h * 4 + 0] + psum[h * 4 + 1] + psum[h * 4 + 2] + psum[h * 4 + 3];
    const float scale = rsqrtf(tot / 256.f + 1e-5f);
    fused[idx] = f2bs(f * scale * onw[dd]);
}

// ================================================================ launch
extern "C" void kernel_launch(void* const* d_in, const int* in_sizes, int n_in,
                              void* d_out, int out_size, void* d_ws, size_t ws_size,
                              hipStream_t stream) {
    const float* hs   = (const float*)d_in[0];
    const float* q_w  = (const float*)d_in[1];
    const float* k_w  = (const float*)d_in[2];
    const float* v_w  = (const float*)d_in[3];
    const float* b_w  = (const float*)d_in[4];
    const float* qc_w = (const float*)d_in[5];
    const float* kc_w = (const float*)d_in[6];
    const float* vc_w = (const float*)d_in[7];
    const float* f1w  = (const float*)d_in[8];
    const float* f3w  = (const float*)d_in[9];
    const float* f7w  = (const float*)d_in[10];
    const float* f31w = (const float*)d_in[11];
    const float* w1   = (const float*)d_in[12];
    const float* b1   = (const float*)d_in[13];
    const float* w2   = (const float*)d_in[14];
    const float* b2   = (const float*)d_in[15];
    const float* glt  = (const float*)d_in[16];
    const float* onw  = (const float*)d_in[17];
    const float* o_w  = (const float*)d_in[18];
    float* out = (float*)d_out;

    const size_t SZ = (size_t)B_ * L_ * D_;  // 4,194,304
    float* qlin = (float*)d_ws;       // qkv[4096][3072] spans qlin..vlin; -> f1b after scan
    float* klin = qlin + SZ;          // -> ktg (bf16) after convs; -> f3b after scan
    float* vlin = klin + SZ;          // -> f7b after scan
    float* qbuf = vlin + SZ;          // normed q fp32; -> hgate later
    float* kbuf = qbuf + SZ;          // normed k fp32; -> fused_bf later
    float* vbuf = kbuf + SZ;          // silu v fp32
    float* f31b = vbuf + SZ;          // start: qwT/kwT/vwT + qbf (all dead before fir)
    float* wb   = f31b + SZ;          // wbf (bf16); after scan: gin_bf + w1T
    float* ub   = wb + SZ;            // u fp32; after scan: owT
    float* dlt  = ub + SZ;            // start: hs_bf (dead before scan)
    float* beta = dlt + SZ;
    float* attn = beta + (size_t)B_ * L_ * H_;
    float* stat = attn + (size_t)B_ * H_ * NC * 1024;
    float* wts  = stat + (size_t)B_ * L_ * H_ * 24;
    float* f1b = qlin;
    float* f3b = klin;
    float* f7b = vlin;
    float* hgate = qbuf;
    float* qkv = qlin;  // [4096][3072]

    // bf16 aliases
    ushort_t* hs_bf = (ushort_t*)dlt;
    ushort_t* qwT = (ushort_t*)f31b;                  // 1M elems
    ushort_t* kwT = (ushort_t*)f31b + 1048576;
    ushort_t* vwT = (ushort_t*)f31b + 2097152;
    ushort_t* qbf = (ushort_t*)f31b + 3145728;        // SZ bf16, ends at 7.3M elems < 8.4M
    ushort_t* gin_bf = (ushort_t*)wb;
    ushort_t* w1T = (ushort_t*)(wb + 2359296);
    ushort_t* owT = (ushort_t*)ub;
    ushort_t* fused_bf = (ushort_t*)kbuf;
    ushort_t* ktg = (ushort_t*)klin;   // live [attn_k .. scan]
    ushort_t* wbf = (ushort_t*)wb;     // live [prep_k .. scan]
    ushort_t* at_bf = (ushort_t*)attn; // live [attn_k .. scan]

    const int M = B_ * L_;  // 4096

    // weight transposes + activation cast
    tcast_k<<<dim3(32, 32), 256, 0, stream>>>(q_w, qwT, 1024, 1024);
    tcast_k<<<dim3(32, 32), 256, 0, stream>>>(k_w, kwT, 1024, 1024);
    tcast_k<<<dim3(32, 32), 256, 0, stream>>>(v_w, vwT, 1024, 1024);
    cast_k<<<4096, 256, 0, stream>>>(hs, hs_bf);
    // fused q|k|v projection (wT tensors are contiguous): qkv[M][3072]
    gemm_bf<0><<<dim3(24, 32), 256, 0, stream>>>(hs_bf, qwT, nullptr, qkv, M, 3072, 1024);
    beta_k<<<M, 64, 0, stream>>>(hs, b_w, beta);
    // fused conv+silu(+l2norm)
    convql_k<1, 1><<<512, 256, 0, stream>>>(qkv + 0,    qc_w, qbuf, qbf);
    convql_k<1, 0><<<512, 256, 0, stream>>>(qkv + 1024, kc_w, kbuf, nullptr);
    convql_k<0, 0><<<512, 256, 0, stream>>>(qkv + 2048, vc_w, vbuf, nullptr);
    // chunkwise delta rule
    prep_k<<<B_ * H_ * NC, 256, 0, stream>>>(kbuf, vbuf, beta, wbf, ub);
    attn_k<<<B_ * H_ * NC, 256, 0, stream>>>(qbuf, kbuf, at_bf, ktg);
    scan3_k<<<128, 256, 0, stream>>>(qbf, wbf, ub, at_bf, ktg, dlt);
    // fused FIR branches
    fir_k<<<512, 256, 0, stream>>>(vbuf, f1w, f3w, f7w, f31w, f1b, f3b, f7b, f31b);
    // gate
    stats_k<<<M * H_, 64, 0, stream>>>(f1b, f3b, f7b, f31b, dlt, vbuf, stat);
    gatein_k<<<17920, 256, 0, stream>>>(hs, stat, gin_bf);
    tcast_k<<<dim3(32, 35), 256, 0, stream>>>(w1, w1T, 1120, 1024);
    gemm_bf<1><<<dim3(8, 32), 256, 0, stream>>>(gin_bf, w1T, b1, hgate, M, 1024, 1120);
    wts_k<<<M, 256, 0, stream>>>(hgate, w2, b2, glt, wts);
    fuse_k<<<M, 1024, 0, stream>>>(f1b, f3b, f7b, f31b, dlt, vbuf, wts, onw, fused_bf);
    // output projection
    tcast_k<<<dim3(32, 32), 256, 0, stream>>>(o_w, owT, 1024, 1024);
    gemm_bf<0><<<dim3(8, 32), 256, 0, stream>>>(fused_bf, owT, nullptr, out, M, 1024, 1024);
}

// Round 6
// 591.590 us; speedup vs baseline: 3.7752x; 1.0753x over previous
//
#include <hip/hip_runtime.h>
#include <hip/hip_bf16.h>
#include <math.h>

#define B_ 2
#define L_ 2048
#define D_ 1024
#define H_ 4
#define NC 64   // chunks per sequence

typedef unsigned short ushort_t;
typedef __bf16 bf16x8 __attribute__((ext_vector_type(8)));
typedef float f32x4 __attribute__((ext_vector_type(4)));
typedef ushort_t u16x8 __attribute__((ext_vector_type(8)));

__device__ __forceinline__ ushort_t f2bs(float f) {
    __hip_bfloat16 h = __float2bfloat16(f);
    ushort_t u;
    __builtin_memcpy(&u, &h, 2);
    return u;
}

__device__ __forceinline__ float wred(float v) {
    v += __shfl_down(v, 32);
    v += __shfl_down(v, 16);
    v += __shfl_down(v, 8);
    v += __shfl_down(v, 4);
    v += __shfl_down(v, 2);
    v += __shfl_down(v, 1);
    return v;
}

__device__ __forceinline__ void gload16(const void* g, void* l) {
    __builtin_amdgcn_global_load_lds((const __attribute__((address_space(1))) void*)g,
                                     (__attribute__((address_space(3))) void*)l, 16, 0, 0);
}

// raw barrier: drain LDS only, leave vmcnt (global loads) in flight
#define LGKM0_BAR()                                          \
    do {                                                     \
        asm volatile("s_waitcnt lgkmcnt(0)" ::: "memory");   \
        __builtin_amdgcn_s_barrier();                        \
    } while (0)

// ------------------------------------------- transpose+cast: W[K][N] f32 -> WT[N][K] bf16
__global__ __launch_bounds__(256) void tcast_k(const float* __restrict__ W,
                                               ushort_t* __restrict__ WT, int K, int N) {
    __shared__ float tile[32 * 33];
    const int k0 = blockIdx.y << 5, n0 = blockIdx.x << 5;
    for (int e = threadIdx.x; e < 1024; e += 256)
        tile[(e >> 5) * 33 + (e & 31)] = W[(size_t)(k0 + (e >> 5)) * N + n0 + (e & 31)];
    __syncthreads();
    for (int e = threadIdx.x; e < 1024; e += 256)
        WT[(size_t)(n0 + (e >> 5)) * K + k0 + (e & 31)] = f2bs(tile[(e & 31) * 33 + (e >> 5)]);
}

// ------------------------------------------- cast f32 -> bf16 flat
__global__ __launch_bounds__(256) void cast_k(const float* __restrict__ x,
                                              ushort_t* __restrict__ y) {
    const int i = blockIdx.x * 256 + threadIdx.x;
    const float4 v = *(const float4*)&x[(size_t)i * 4];
    ushort4 p;
    p.x = f2bs(v.x); p.y = f2bs(v.y); p.z = f2bs(v.z); p.w = f2bs(v.w);
    *(ushort4*)&y[(size_t)i * 4] = p;
}

// ------------------------------------------- bf16 MFMA GEMM (TN): C = act(A @ Bt^T + bias)
template <int ACT>
__global__ __launch_bounds__(256) void gemm_bf(const ushort_t* __restrict__ A,
                                               const ushort_t* __restrict__ Bt,
                                               const float* __restrict__ bias,
                                               float* __restrict__ C,
                                               int M, int N, int K) {
    __shared__ ushort_t As[128 * 32];
    __shared__ ushort_t Bs[128 * 32];
    const int t = threadIdx.x;
    const int wv = t >> 6, l = t & 63;
    const int m0 = blockIdx.y << 7, n0 = blockIdx.x << 7;
    const int wm = wv & 1, wn = wv >> 1;
    const int q4 = l >> 4, c16 = l & 15;
    f32x4 acc[4][4];
#pragma unroll
    for (int i = 0; i < 4; ++i)
#pragma unroll
        for (int j = 0; j < 4; ++j) {
            f32x4 z = {0.f, 0.f, 0.f, 0.f};
            acc[i][j] = z;
        }
    const int srow = (l >> 2);
    const int scol = (l & 3) << 3;
    for (int k0 = 0; k0 < K; k0 += 32) {
        __syncthreads();
#pragma unroll
        for (int si = 0; si < 2; ++si) {
            const int s = wv * 2 + si;
            gload16(&A[(size_t)(m0 + s * 16 + srow) * K + k0 + scol], &As[s * 512]);
            gload16(&Bt[(size_t)(n0 + s * 16 + srow) * K + k0 + scol], &Bs[s * 512]);
        }
        __syncthreads();
        bf16x8 af[4], bff[4];
#pragma unroll
        for (int mi = 0; mi < 4; ++mi)
            af[mi] = *(const bf16x8*)&As[(wm * 64 + mi * 16 + c16) * 32 + q4 * 8];
#pragma unroll
        for (int ni = 0; ni < 4; ++ni)
            bff[ni] = *(const bf16x8*)&Bs[(wn * 64 + ni * 16 + c16) * 32 + q4 * 8];
#pragma unroll
        for (int mi = 0; mi < 4; ++mi)
#pragma unroll
            for (int ni = 0; ni < 4; ++ni)
                acc[mi][ni] = __builtin_amdgcn_mfma_f32_16x16x32_bf16(af[mi], bff[ni],
                                                                     acc[mi][ni], 0, 0, 0);
    }
#pragma unroll
    for (int mi = 0; mi < 4; ++mi)
#pragma unroll
        for (int ni = 0; ni < 4; ++ni)
#pragma unroll
            for (int r = 0; r < 4; ++r) {
                const int row = m0 + wm * 64 + mi * 16 + q4 * 4 + r;
                const int col = n0 + wn * 64 + ni * 16 + c16;
                float v = acc[mi][ni][r];
                if (ACT == 1) {
                    v += bias[col];
                    v = 0.5f * v * (1.0f + erff(v * 0.70710678118654752f));
                }
                C[(size_t)row * N + col] = v;
            }
}

// ---------------- fused causal conv(K=4) + silu (+ row l2norm), LDS-tiled
// X row stride 3072 (qkv fused buffer); one block = (b, 32 l-rows, head)
template <int DO_NORM, int EMIT_F32, int EMIT_BF>
__global__ __launch_bounds__(256) void convql_k(const float* __restrict__ X,
                                                const float* __restrict__ cw,
                                                float* __restrict__ Y,
                                                ushort_t* __restrict__ Ybf) {
    __shared__ float xs[35 * 256];
    const int bid = blockIdx.x;
    const int h = bid & 3, lt = (bid >> 2) & 63, b = bid >> 8;
    const int t = threadIdx.x;
    const int l0 = lt << 5;
    const int cg = (h << 8) | t;
    for (int e = t; e < 35 * 256; e += 256) {
        const int r = e >> 8, c = e & 255;
        const int gl = l0 + r - 3;
        xs[e] = (gl >= 0) ? X[((size_t)(b * L_) + gl) * 3072 + (h << 8) + c] : 0.f;
    }
    const float w0 = cw[cg * 4 + 0], w1 = cw[cg * 4 + 1];
    const float w2 = cw[cg * 4 + 2], w3 = cw[cg * 4 + 3];
    __syncthreads();
    float yr[32];
#pragma unroll
    for (int l = 0; l < 32; ++l) {
        const float a = xs[(l + 0) * 256 + t] * w0 + xs[(l + 1) * 256 + t] * w1 +
                        xs[(l + 2) * 256 + t] * w2 + xs[(l + 3) * 256 + t] * w3;
        yr[l] = a / (1.f + expf(-a));
    }
    if (DO_NORM) {
        __syncthreads();
#pragma unroll
        for (int l = 0; l < 32; ++l) xs[l * 256 + t] = yr[l];
        __syncthreads();
        const int wv = t >> 6, lane = t & 63;
#pragma unroll
        for (int ri = 0; ri < 8; ++ri) {
            const int r = wv * 8 + ri;
            float4 v = *(float4*)&xs[r * 256 + lane * 4];
            float ss = v.x * v.x + v.y * v.y + v.z * v.z + v.w * v.w;
            ss = wred(ss);
            ss = __shfl(ss, 0);
            const float s = rsqrtf(ss + 1e-6f);
            v.x *= s; v.y *= s; v.z *= s; v.w *= s;
            const size_t go = ((size_t)(b * L_) + l0 + r) * 1024 + (h << 8) + lane * 4;
            if (EMIT_F32) *(float4*)&Y[go] = v;
            if (EMIT_BF) {
                ushort4 p;
                p.x = f2bs(v.x); p.y = f2bs(v.y); p.z = f2bs(v.z); p.w = f2bs(v.w);
                *(ushort4*)&Ybf[go] = p;
            }
        }
    } else {
#pragma unroll
        for (int l = 0; l < 32; ++l)
            if (EMIT_F32) Y[((size_t)(b * L_) + l0 + l) * 1024 + cg] = yr[l];
    }
}

// ---------------- fused FIR branches (K=1,3,7,31), LDS-tiled, one read of v
__global__ __launch_bounds__(256) void fir_k(const float* __restrict__ V,
                                             const float* __restrict__ w1w,
                                             const float* __restrict__ w3w,
                                             const float* __restrict__ w7w,
                                             const float* __restrict__ w31w,
                                             float* __restrict__ o1,
                                             float* __restrict__ o3,
                                             float* __restrict__ o7,
                                             float* __restrict__ o31) {
    __shared__ float xs[62 * 256];
    const int bid = blockIdx.x;
    const int h = bid & 3, lt = (bid >> 2) & 63, b = bid >> 8;
    const int t = threadIdx.x;
    const int l0 = lt << 5;
    const int cg = (h << 8) | t;
    for (int e = t; e < 62 * 256; e += 256) {
        const int r = e >> 8, c = e & 255;
        const int gl = l0 + r - 30;
        xs[e] = (gl >= 0) ? V[((size_t)(b * L_) + gl) * 1024 + (h << 8) + c] : 0.f;
    }
    float lw31[31], lw7[7], lw3[3];
#pragma unroll
    for (int j = 0; j < 31; ++j) lw31[j] = w31w[cg * 31 + j];
#pragma unroll
    for (int j = 0; j < 7; ++j) lw7[j] = w7w[cg * 7 + j];
#pragma unroll
    for (int j = 0; j < 3; ++j) lw3[j] = w3w[cg * 3 + j];
    const float lw1 = w1w[cg];
    __syncthreads();
    for (int l = 0; l < 32; ++l) {
        float a31 = 0.f, a7 = 0.f, a3 = 0.f, v = 0.f;
#pragma unroll
        for (int j = 0; j < 31; ++j) {
            v = xs[(l + j) * 256 + t];
            a31 += v * lw31[j];
            if (j >= 24) a7 += v * lw7[j - 24];
            if (j >= 28) a3 += v * lw3[j - 28];
        }
        const size_t go = ((size_t)(b * L_) + l0 + l) * 1024 + cg;
        o31[go] = a31;
        o7[go] = a7;
        o3[go] = a3;
        o1[go] = v * lw1;
    }
}

// ------------------- beta = sigmoid(hs @ b_w); also emit gate_in hs-part (bf16)
__global__ __launch_bounds__(64) void beta_k(const float* __restrict__ hs,
                                             const float* __restrict__ bw,
                                             float* __restrict__ beta,
                                             ushort_t* __restrict__ gin) {
    const int row = blockIdx.x;
    const int lane = threadIdx.x;
    float a0 = 0, a1 = 0, a2 = 0, a3 = 0;
    const float* hp = hs + (size_t)row * D_;
    ushort_t* gp = gin + (size_t)row * 1120;
    for (int c = lane; c < D_; c += 64) {
        const float x = hp[c];
        gp[c] = f2bs(x);
        a0 += x * bw[c * 4 + 0];
        a1 += x * bw[c * 4 + 1];
        a2 += x * bw[c * 4 + 2];
        a3 += x * bw[c * 4 + 3];
    }
    a0 = wred(a0); a1 = wred(a1); a2 = wred(a2); a3 = wred(a3);
    if (lane == 0) {
        float* o = beta + (size_t)row * 4;
        o[0] = 1.f / (1.f + expf(-a0));
        o[1] = 1.f / (1.f + expf(-a1));
        o[2] = 1.f / (1.f + expf(-a2));
        o[3] = 1.f / (1.f + expf(-a3));
    }
}

// --------------- fused MFMA delta-prep: G=k@kT, attn=tril(q@kT), T=(I-A)^-1,
// w = T'@k, u = T'@v (beta folded into T'), exports wbf/ub/atg/ktg
__global__ __launch_bounds__(256) void prep2_k(const ushort_t* __restrict__ qbf,
                                               const ushort_t* __restrict__ kbf,
                                               const float* __restrict__ vg,
                                               const float* __restrict__ beta,
                                               ushort_t* __restrict__ wbf,
                                               float* __restrict__ ub,
                                               ushort_t* __restrict__ atg,
                                               ushort_t* __restrict__ ktg) {
    __shared__ ushort_t k_lds[32 * 264];   // plain rows (for transpose)
    __shared__ ushort_t kT_lds[256 * 32];  // swizzled: seg s at (s ^ ((c>>1)&3))
    __shared__ ushort_t vT_lds[256 * 32];  // same swizzle
    __shared__ float Am[32 * 33];
    __shared__ float Tm[32 * 33];
    __shared__ ushort_t Tb[32 * 40];       // T' bf16, 16B-aligned rows
    __shared__ float beta_s[32];
    const int bid = blockIdx.x;  // bh*NC + ci
    const int bh = bid >> 6, ci = bid & 63;
    const int b = bh >> 2, h = bh & 3;
    const int t = threadIdx.x;
    const int wv = t >> 6, lane = t & 63;
    const int l16 = lane & 15, quad = lane >> 4;
    const size_t cb = (size_t)bid;
    const size_t grow = ((size_t)(b * L_ + ci * 32)) * 1024 + (h << 8);
    const f32x4 z4 = {0.f, 0.f, 0.f, 0.f};

    if (t < 32) beta_s[t] = beta[(size_t)(b * L_ + ci * 32 + t) * 4 + h];
    // stage k rows (plain, padded)
#pragma unroll
    for (int j = 0; j < 4; ++j) {
        const int idx = j * 2048 + t * 8, r = idx >> 8, c = idx & 255;
        *(u16x8*)&k_lds[r * 264 + c] = *(const u16x8*)&kbf[grow + (size_t)r * 1024 + c];
    }
    // build vT (bf16, swizzled) from global v
#pragma unroll
    for (int j = 0; j < 8; ++j) {
        const int e = j * 1024 + t * 4, r = e >> 8, c = e & 255;
        const float4 v4 = *(const float4*)&vg[grow + (size_t)r * 1024 + c];
        const float vv[4] = {v4.x, v4.y, v4.z, v4.w};
#pragma unroll
        for (int x = 0; x < 4; ++x) {
            const int cc = c + x;
            const int sp = (r >> 3) ^ ((cc >> 1) & 3);
            vT_lds[cc * 32 + sp * 8 + (r & 7)] = f2bs(vv[x]);
        }
    }
    // G = k@kT and attn = q@kT from global register fragments
    const int mi = wv & 1, ni = wv >> 1;
    f32x4 g = z4, atv = z4;
#pragma unroll
    for (int s = 0; s < 8; ++s) {
        const bf16x8 a =
            *(const bf16x8*)&kbf[grow + (size_t)(mi * 16 + l16) * 1024 + s * 32 + (quad << 3)];
        const bf16x8 bb =
            *(const bf16x8*)&kbf[grow + (size_t)(ni * 16 + l16) * 1024 + s * 32 + (quad << 3)];
        const bf16x8 qa =
            *(const bf16x8*)&qbf[grow + (size_t)(mi * 16 + l16) * 1024 + s * 32 + (quad << 3)];
        g = __builtin_amdgcn_mfma_f32_16x16x32_bf16(a, bb, g, 0, 0, 0);
        atv = __builtin_amdgcn_mfma_f32_16x16x32_bf16(qa, bb, atv, 0, 0, 0);
    }
    __syncthreads();  // beta_s + k_lds visible
    // Am / Tm init / attn export
#pragma unroll
    for (int r = 0; r < 4; ++r) {
        const int row = mi * 16 + (quad << 2) + r;
        const int col = ni * 16 + l16;
        Am[row * 33 + col] = (col < row) ? -beta_s[row] * g[r] : 0.f;
        Tm[row * 33 + col] = (row == col) ? 1.f : 0.f;
        atg[cb * 1024 + row * 32 + col] = (col <= row) ? f2bs(atv[r]) : (ushort_t)0;
    }
    // build kT (swizzled) from k_lds
#pragma unroll
    for (int j = 0; j < 8; ++j) {
        const int e = j * 1024 + t * 4, r = e >> 8, c = e & 255;
#pragma unroll
        for (int x = 0; x < 4; ++x) {
            const int cc = c + x;
            const int sp = (r >> 3) ^ ((cc >> 1) & 3);
            kT_lds[cc * 32 + sp * 8 + (r & 7)] = k_lds[r * 264 + cc];
        }
    }
    __syncthreads();
    // forward substitution: T[i] += sum_{j<i} A[i][j] T[j]
    for (int i = 1; i < 32; ++i) {
        if (t < 32) {
            float s = 0.f;
            for (int j = 0; j < i; ++j) s += Am[i * 33 + j] * Tm[j * 33 + t];
            Tm[i * 33 + t] += s;
        }
        __syncthreads();
    }
    // Tb = bf16(T * beta_col)  (T' — beta folded in)
#pragma unroll
    for (int j = 0; j < 4; ++j) {
        const int e = j * 256 + t, i = e >> 5, jj = e & 31;
        Tb[i * 40 + jj] = f2bs(Tm[i * 33 + jj] * beta_s[jj]);
    }
    __syncthreads();
    // w = T'@k, u = T'@v  (M=32,N=256,K=32) — 8 n-tiles per wave
    const bf16x8 tf = *(const bf16x8*)&Tb[(mi * 16 + l16) * 40 + (quad << 3)];
#pragma unroll
    for (int j = 0; j < 8; ++j) {
        const int nt = ni * 8 + j;
        const int d = (nt << 4) + l16;
        const int sp = quad ^ ((d >> 1) & 3);
        const bf16x8 kb = *(const bf16x8*)&kT_lds[d * 32 + (sp << 3)];
        const bf16x8 vb = *(const bf16x8*)&vT_lds[d * 32 + (sp << 3)];
        const f32x4 wacc = __builtin_amdgcn_mfma_f32_16x16x32_bf16(tf, kb, z4, 0, 0, 0);
        const f32x4 uacc = __builtin_amdgcn_mfma_f32_16x16x32_bf16(tf, vb, z4, 0, 0, 0);
#pragma unroll
        for (int r = 0; r < 4; ++r) {
            const int row = mi * 16 + (quad << 2) + r;
            wbf[cb * 8192 + row * 256 + d] = f2bs(wacc[r]);
            ub[cb * 8192 + (size_t)row * 256 + d] = uacc[r];
        }
    }
    // export ktg (plain [c][i] layout)
#pragma unroll
    for (int j = 0; j < 4; ++j) {
        const int idx = j * 2048 + t * 8;
        const int c = idx >> 5, sl = (idx & 31) >> 3;
        const int sp = sl ^ ((c >> 1) & 3);
        *(u16x8*)&ktg[cb * 8192 + c * 32 + sl * 8] = *(const u16x8*)&kT_lds[c * 32 + sp * 8];
    }
}

// ---------------------- MFMA scan, register-fragment double buffer, raw barriers
__global__ __launch_bounds__(256, 1) void scan4_k(const ushort_t* __restrict__ qbf,
                                                  const ushort_t* __restrict__ wbf,
                                                  const float* __restrict__ ubuf,
                                                  const ushort_t* __restrict__ atg,
                                                  const ushort_t* __restrict__ ktg,
                                                  float* __restrict__ dlt) {
    __shared__ ushort_t uh_lds[16 * 40];
    __shared__ ushort_t S_lds[16 * 264];
    const int t = threadIdx.x;
    const int wv = t >> 6, lane = t & 63;
    const int bh = blockIdx.x & 7, tile = blockIdx.x >> 3;
    const int b = bh >> 2, h = bh & 3;
    const int l16 = lane & 15, quad = lane >> 4;
    for (int e = t; e < 16 * 264; e += 256) S_lds[e] = 0;

    f32x4 Sacc[8];
#pragma unroll
    for (int j = 0; j < 8; ++j) {
        f32x4 z = {0.f, 0.f, 0.f, 0.f};
        Sacc[j] = z;
    }

    bf16x8 wfA[8], qfA[8], atfA, ktA[8];
    bf16x8 wfB[8], qfB[8], atfB, ktB[8];
    float uvA[4], uvB[4];

    auto loadf = [&](int ci, bf16x8* wf, bf16x8* qf, bf16x8& atf, float* uv, bf16x8* ktf) {
        const size_t cb = (size_t)(bh * NC + ci);
        if (wv < 2) {
            const ushort_t* wsrc = wbf + cb * 8192;
            const ushort_t* qsrc = qbf + ((size_t)(b * L_ + ci * 32)) * 1024 + (h << 8);
            const int i = (wv << 4) + l16;
#pragma unroll
            for (int s = 0; s < 8; ++s) {
                wf[s] = *(const bf16x8*)&wsrc[i * 256 + s * 32 + (quad << 3)];
                qf[s] = *(const bf16x8*)&qsrc[(size_t)i * 1024 + s * 32 + (quad << 3)];
            }
            atf = *(const bf16x8*)&atg[cb * 1024 + i * 32 + (quad << 3)];
#pragma unroll
            for (int r = 0; r < 4; ++r)
                uv[r] = ubuf[cb * 8192 + (size_t)((wv << 4) + (quad << 2) + r) * 256 +
                             (tile << 4) + l16];
        } else {
            const ushort_t* ksrc = ktg + cb * 8192;
#pragma unroll
            for (int j = 0; j < 8; ++j) {
                const int c = ((((wv - 2) << 3) + j) << 4) + l16;
                ktf[j] = *(const bf16x8*)&ksrc[c * 32 + (quad << 3)];
            }
        }
    };
    auto sfrag = [&](int k0) -> bf16x8 {
        return *(const bf16x8*)&S_lds[l16 * 264 + k0 + (quad << 3)];
    };
    auto uhfrag = [&]() -> bf16x8 {
        return *(const bf16x8*)&uh_lds[l16 * 40 + (quad << 3)];
    };
    auto compute = [&](int ci, bf16x8* wf, bf16x8* qf, bf16x8& atf, float* uv, bf16x8* ktf) {
        const size_t gbase = ((size_t)(b * L_ + ci * 32)) * D_ + (h << 8);
        if (wv < 2) {
            f32x4 acc = {0.f, 0.f, 0.f, 0.f};
#pragma unroll
            for (int s = 0; s < 8; ++s)
                acc = __builtin_amdgcn_mfma_f32_16x16x32_bf16(wf[s], sfrag(s * 32), acc, 0, 0, 0);
            ushort4 up;
            up.x = f2bs(uv[0] - acc[0]);
            up.y = f2bs(uv[1] - acc[1]);
            up.z = f2bs(uv[2] - acc[2]);
            up.w = f2bs(uv[3] - acc[3]);
            *(ushort4*)&uh_lds[l16 * 40 + (wv << 4) + (quad << 2)] = up;
        }
        LGKM0_BAR();  // uh visible
        if (wv < 2) {
            f32x4 o = {0.f, 0.f, 0.f, 0.f};
#pragma unroll
            for (int s = 0; s < 8; ++s)
                o = __builtin_amdgcn_mfma_f32_16x16x32_bf16(qf[s], sfrag(s * 32), o, 0, 0, 0);
            o = __builtin_amdgcn_mfma_f32_16x16x32_bf16(atf, uhfrag(), o, 0, 0, 0);
#pragma unroll
            for (int r = 0; r < 4; ++r)
                dlt[gbase + (size_t)((wv << 4) + (quad << 2) + r) * D_ + (tile << 4) + l16] =
                    o[r];
        } else {
            const bf16x8 uf = uhfrag();
#pragma unroll
            for (int j = 0; j < 8; ++j)
                Sacc[j] = __builtin_amdgcn_mfma_f32_16x16x32_bf16(ktf[j], uf, Sacc[j], 0, 0, 0);
        }
        LGKM0_BAR();  // phase2's S reads drained
        if (wv >= 2) {
#pragma unroll
            for (int j = 0; j < 8; ++j) {
                const int c0 = ((((wv - 2) << 3) + j) << 4) + (quad << 2);
#pragma unroll
                for (int r = 0; r < 4; ++r)
                    S_lds[l16 * 264 + c0 + r] = f2bs(Sacc[j][r]);
            }
        }
        LGKM0_BAR();  // mirror visible for next chunk
    };

    loadf(0, wfA, qfA, atfA, uvA, ktA);
    LGKM0_BAR();  // S zero-init visible
    for (int ci = 0; ci < NC; ci += 2) {
        loadf(ci + 1, wfB, qfB, atfB, uvB, ktB);
        compute(ci, wfA, qfA, atfA, uvA, ktA);
        if (ci + 2 < NC) loadf(ci + 2, wfA, qfA, atfA, uvA, ktA);
        compute(ci + 1, wfB, qfB, atfB, uvB, ktB);
    }
}

// ---------------- branch stats -> gate_in stat columns (bf16)
__global__ __launch_bounds__(64) void stats_k(const float* __restrict__ f1,
                                              const float* __restrict__ f3,
                                              const float* __restrict__ f7,
                                              const float* __restrict__ f31,
                                              const float* __restrict__ dl,
                                              const float* __restrict__ vv,
                                              ushort_t* __restrict__ gin) {
    const int row = blockIdx.x;  // (b*L+l)*H + h
    const int lane = threadIdx.x;
    const float* ptrs[6] = {f1, f3, f7, f31, dl, vv};
    const size_t base = (size_t)row * 256;
    ushort_t* gp = gin + (size_t)(row >> 2) * 1120 + 1024 + (row & 3) * 24;
    for (int br = 0; br < 6; ++br) {
        const float4 x = *(const float4*)&ptrs[br][base + lane * 4];
        float s1 = x.x + x.y + x.z + x.w;
        float s2 = x.x * x.x + x.y * x.y + x.z * x.z + x.w * x.w;
        float sa = fabsf(x.x) + fabsf(x.y) + fabsf(x.z) + fabsf(x.w);
        s1 = wred(s1); s2 = wred(s2); sa = wred(sa);
        if (lane == 0) {
            const float m = s1 / 256.f;
            float var = (s2 - 256.f * m * m) / 255.f;
            if (var < 0.f) var = 0.f;
            gp[br * 4 + 0] = f2bs(m);
            gp[br * 4 + 1] = f2bs(sqrtf(var));
            gp[br * 4 + 2] = f2bs(sa / 256.f);
            gp[br * 4 + 3] = f2bs(sqrtf(s2));
        }
    }
}

// ---------------------------------------------- logits -> softmax weights
__global__ __launch_bounds__(256) void wts_k(const float* __restrict__ hg,
                                             const float* __restrict__ w2,
                                             const float* __restrict__ b2,
                                             const float* __restrict__ glt,
                                             float* __restrict__ wts) {
    const int row = blockIdx.x;
    const int h = threadIdx.x >> 6, lane = threadIdx.x & 63;
    float hv[16];
    const float* hp = hg + (size_t)row * 1024;
#pragma unroll
    for (int ii = 0; ii < 16; ++ii) hv[ii] = hp[lane + 64 * ii];
    float lg[6];
#pragma unroll
    for (int s = 0; s < 6; ++s) {
        const int j = h * 6 + s;
        float acc = 0.f;
#pragma unroll
        for (int ii = 0; ii < 16; ++ii) acc += hv[ii] * w2[(size_t)(lane + 64 * ii) * 24 + j];
        lg[s] = wred(acc);
    }
    if (lane == 0) {
        const float temp = log1pf(expf(glt[h])) + 0.5f;
        float mx = -1e30f;
#pragma unroll
        for (int s = 0; s < 6; ++s) {
            lg[s] = (lg[s] + b2[h * 6 + s]) / temp;
            mx = fmaxf(mx, lg[s]);
        }
        float se = 0.f;
#pragma unroll
        for (int s = 0; s < 6; ++s) {
            lg[s] = expf(lg[s] - mx);
            se += lg[s];
        }
        float* o = &wts[(size_t)row * 24 + h * 6];
        const float inv = 1.f / se;
#pragma unroll
        for (int s = 0; s < 6; ++s) o[s] = lg[s] * inv;
    }
}

// -------------------------------------- fused = RMSNorm(sum ws*branch) * onorm_w (bf16 out)
__global__ __launch_bounds__(1024) void fuse_k(const float* __restrict__ f1,
                                               const float* __restrict__ f3,
                                               const float* __restrict__ f7,
                                               const float* __restrict__ f31,
                                               const float* __restrict__ dl,
                                               const float* __restrict__ vv,
                                               const float* __restrict__ wts,
                                               const float* __restrict__ onw,
                                               ushort_t* __restrict__ fused) {
    __shared__ float wloc[24];
    __shared__ float psum[16];
    const int row = blockIdx.x, t = threadIdx.x;
    if (t < 24) wloc[t] = wts[(size_t)row * 24 + t];
    __syncthreads();
    const int h = t >> 8, dd = t & 255;
    const size_t idx = (size_t)row * 1024 + t;
    const float* ptrs[6] = {f1, f3, f7, f31, dl, vv};
    float f = 0.f;
#pragma unroll
    for (int br = 0; br < 6; ++br) f += wloc[h * 6 + br] * ptrs[br][idx];
    float ss = wred(f * f);
    const int wave = t >> 6;
    if ((t & 63) == 0) psum[wave] = ss;
    __syncthreads();
    const float tot = psum[h * 4 + 0] + psum[h * 4 + 1] + psum[h * 4 + 2] + psum[h * 4 + 3];
    const float scale = rsqrtf(tot / 256.f + 1e-5f);
    fused[idx] = f2bs(f * scale * onw[dd]);
}

// ================================================================ launch
extern "C" void kernel_launch(void* const* d_in, const int* in_sizes, int n_in,
                              void* d_out, int out_size, void* d_ws, size_t ws_size,
                              hipStream_t stream) {
    const float* hs   = (const float*)d_in[0];
    const float* q_w  = (const float*)d_in[1];
    const float* k_w  = (const float*)d_in[2];
    const float* v_w  = (const float*)d_in[3];
    const float* b_w  = (const float*)d_in[4];
    const float* qc_w = (const float*)d_in[5];
    const float* kc_w = (const float*)d_in[6];
    const float* vc_w = (const float*)d_in[7];
    const float* f1w  = (const float*)d_in[8];
    const float* f3w  = (const float*)d_in[9];
    const float* f7w  = (const float*)d_in[10];
    const float* f31w = (const float*)d_in[11];
    const float* w1   = (const float*)d_in[12];
    const float* b1   = (const float*)d_in[13];
    const float* w2   = (const float*)d_in[14];
    const float* b2   = (const float*)d_in[15];
    const float* glt  = (const float*)d_in[16];
    const float* onw  = (const float*)d_in[17];
    const float* o_w  = (const float*)d_in[18];
    float* out = (float*)d_out;

    const size_t SZ = (size_t)B_ * L_ * D_;  // 4,194,304
    float* qlin = (float*)d_ws;       // qkv[4096][3072] spans 3*SZ; f1b after scan
    float* klin = qlin + SZ;          // ktg bf16 [prep2..scan]; f3b after scan
    float* vlin = klin + SZ;          // f7b after scan
    float* qbuf = vlin + SZ;          // gin_bf (bf16) [beta_k .. gate gemm]
    float* kbuf = qbuf + SZ;          // kbf bf16 [conv..prep2]; hgate fp32; fused_bf
    float* vbuf = kbuf + SZ;          // v fp32 (silu)
    float* f31b = vbuf + SZ;          // qwT/kwT/vwT early; qbf bf16 [conv..scan]; f31 after
    float* wb   = f31b + SZ;          // wbf bf16 [prep2..scan]; w1T after scan
    float* ub   = wb + SZ;            // u fp32 [prep2..scan]; owT after
    float* dlt  = ub + SZ;            // hs_bf early; dlt fp32 [scan..fuse]
    float* beta = dlt + SZ;
    float* attn = beta + (size_t)B_ * L_ * H_;   // at_bf bf16
    float* stat = attn + (size_t)B_ * H_ * NC * 1024;
    float* wts  = stat + (size_t)B_ * L_ * H_ * 24;
    float* f1b = qlin;
    float* f3b = klin;
    float* f7b = vlin;
    float* hgate = kbuf;
    float* qkv = qlin;  // [4096][3072]

    // bf16 aliases
    ushort_t* hs_bf = (ushort_t*)dlt;
    ushort_t* qwT = (ushort_t*)f31b;
    ushort_t* kwT = (ushort_t*)f31b + 1048576;
    ushort_t* vwT = (ushort_t*)f31b + 2097152;
    ushort_t* qbf = (ushort_t*)f31b + 3145728;
    ushort_t* kbf = (ushort_t*)kbuf;
    ushort_t* gin_bf = (ushort_t*)qbuf;
    ushort_t* w1T = (ushort_t*)(wb + 2359296);
    ushort_t* owT = (ushort_t*)ub;
    ushort_t* fused_bf = (ushort_t*)kbuf;
    ushort_t* ktg = (ushort_t*)klin;
    ushort_t* wbf = (ushort_t*)wb;
    ushort_t* at_bf = (ushort_t*)attn;
    (void)stat;

    const int M = B_ * L_;  // 4096

    // weight transposes + activation cast
    tcast_k<<<dim3(32, 32), 256, 0, stream>>>(q_w, qwT, 1024, 1024);
    tcast_k<<<dim3(32, 32), 256, 0, stream>>>(k_w, kwT, 1024, 1024);
    tcast_k<<<dim3(32, 32), 256, 0, stream>>>(v_w, vwT, 1024, 1024);
    cast_k<<<4096, 256, 0, stream>>>(hs, hs_bf);
    // fused q|k|v projection: qkv[M][3072]
    gemm_bf<0><<<dim3(24, 32), 256, 0, stream>>>(hs_bf, qwT, nullptr, qkv, M, 3072, 1024);
    beta_k<<<M, 64, 0, stream>>>(hs, b_w, beta, gin_bf);
    // fused conv+silu(+l2norm): q,k emit bf16 only; v emits fp32
    convql_k<1, 0, 1><<<512, 256, 0, stream>>>(qkv + 0,    qc_w, nullptr, qbf);
    convql_k<1, 0, 1><<<512, 256, 0, stream>>>(qkv + 1024, kc_w, nullptr, kbf);
    convql_k<0, 1, 0><<<512, 256, 0, stream>>>(qkv + 2048, vc_w, vbuf, nullptr);
    // chunkwise delta rule
    prep2_k<<<B_ * H_ * NC, 256, 0, stream>>>(qbf, kbf, vbuf, beta, wbf, ub, at_bf, ktg);
    scan4_k<<<128, 256, 0, stream>>>(qbf, wbf, ub, at_bf, ktg, dlt);
    // fused FIR branches
    fir_k<<<512, 256, 0, stream>>>(vbuf, f1w, f3w, f7w, f31w, f1b, f3b, f7b, f31b);
    // gate
    stats_k<<<M * H_, 64, 0, stream>>>(f1b, f3b, f7b, f31b, dlt, vbuf, gin_bf);
    tcast_k<<<dim3(32, 35), 256, 0, stream>>>(w1, w1T, 1120, 1024);
    gemm_bf<1><<<dim3(8, 32), 256, 0, stream>>>(gin_bf, w1T, b1, hgate, M, 1024, 1120);
    wts_k<<<M, 256, 0, stream>>>(hgate, w2, b2, glt, wts);
    fuse_k<<<M, 1024, 0, stream>>>(f1b, f3b, f7b, f31b, dlt, vbuf, wts, onw, fused_bf);
    // output projection
    tcast_k<<<dim3(32, 32), 256, 0, stream>>>(o_w, owT, 1024, 1024);
    gemm_bf<0><<<dim3(8, 32), 256, 0, stream>>>(fused_bf, owT, nullptr, out, M, 1024, 1024);
}

// Round 7
// 543.992 us; speedup vs baseline: 4.1055x; 1.0875x over previous
//
#include <hip/hip_runtime.h>
#include <hip/hip_bf16.h>
#include <math.h>

#define B_ 2
#define L_ 2048
#define D_ 1024
#define H_ 4
#define NC 64   // chunks per sequence

typedef unsigned short ushort_t;
typedef __bf16 bf16x8 __attribute__((ext_vector_type(8)));
typedef float f32x4 __attribute__((ext_vector_type(4)));
typedef ushort_t u16x8 __attribute__((ext_vector_type(8)));

__device__ __forceinline__ ushort_t f2bs(float f) {
    __hip_bfloat16 h = __float2bfloat16(f);
    ushort_t u;
    __builtin_memcpy(&u, &h, 2);
    return u;
}

__device__ __forceinline__ float wred(float v) {
    v += __shfl_down(v, 32);
    v += __shfl_down(v, 16);
    v += __shfl_down(v, 8);
    v += __shfl_down(v, 4);
    v += __shfl_down(v, 2);
    v += __shfl_down(v, 1);
    return v;
}

__device__ __forceinline__ void gload16(const void* g, void* l) {
    __builtin_amdgcn_global_load_lds((const __attribute__((address_space(1))) void*)g,
                                     (__attribute__((address_space(3))) void*)l, 16, 0, 0);
}

// raw barrier: drain LDS only, leave vmcnt (global loads) in flight
#define LGKM0_BAR()                                          \
    do {                                                     \
        asm volatile("s_waitcnt lgkmcnt(0)" ::: "memory");   \
        __builtin_amdgcn_s_barrier();                        \
    } while (0)

// ------------------------------------------- transpose+cast: W[K][N] f32 -> WT[N][K] bf16
__global__ __launch_bounds__(256) void tcast_k(const float* __restrict__ W,
                                               ushort_t* __restrict__ WT, int K, int N) {
    __shared__ float tile[32 * 33];
    const int k0 = blockIdx.y << 5, n0 = blockIdx.x << 5;
    for (int e = threadIdx.x; e < 1024; e += 256)
        tile[(e >> 5) * 33 + (e & 31)] = W[(size_t)(k0 + (e >> 5)) * N + n0 + (e & 31)];
    __syncthreads();
    for (int e = threadIdx.x; e < 1024; e += 256)
        WT[(size_t)(n0 + (e >> 5)) * K + k0 + (e & 31)] = f2bs(tile[(e & 31) * 33 + (e >> 5)]);
}

// ------------------------------------------- cast f32 -> bf16 flat
__global__ __launch_bounds__(256) void cast_k(const float* __restrict__ x,
                                              ushort_t* __restrict__ y) {
    const int i = blockIdx.x * 256 + threadIdx.x;
    const float4 v = *(const float4*)&x[(size_t)i * 4];
    ushort4 p;
    p.x = f2bs(v.x); p.y = f2bs(v.y); p.z = f2bs(v.z); p.w = f2bs(v.w);
    *(ushort4*)&y[(size_t)i * 4] = p;
}

// ------------------------------------------- bf16 MFMA GEMM (TN): C = act(A @ Bt^T + bias)
template <int ACT>
__global__ __launch_bounds__(256) void gemm_bf(const ushort_t* __restrict__ A,
                                               const ushort_t* __restrict__ Bt,
                                               const float* __restrict__ bias,
                                               float* __restrict__ C,
                                               int M, int N, int K) {
    __shared__ ushort_t As[128 * 32];
    __shared__ ushort_t Bs[128 * 32];
    const int t = threadIdx.x;
    const int wv = t >> 6, l = t & 63;
    const int m0 = blockIdx.y << 7, n0 = blockIdx.x << 7;
    const int wm = wv & 1, wn = wv >> 1;
    const int q4 = l >> 4, c16 = l & 15;
    f32x4 acc[4][4];
#pragma unroll
    for (int i = 0; i < 4; ++i)
#pragma unroll
        for (int j = 0; j < 4; ++j) {
            f32x4 z = {0.f, 0.f, 0.f, 0.f};
            acc[i][j] = z;
        }
    const int srow = (l >> 2);
    const int scol = (l & 3) << 3;
    for (int k0 = 0; k0 < K; k0 += 32) {
        __syncthreads();
#pragma unroll
        for (int si = 0; si < 2; ++si) {
            const int s = wv * 2 + si;
            gload16(&A[(size_t)(m0 + s * 16 + srow) * K + k0 + scol], &As[s * 512]);
            gload16(&Bt[(size_t)(n0 + s * 16 + srow) * K + k0 + scol], &Bs[s * 512]);
        }
        __syncthreads();
        bf16x8 af[4], bff[4];
#pragma unroll
        for (int mi = 0; mi < 4; ++mi)
            af[mi] = *(const bf16x8*)&As[(wm * 64 + mi * 16 + c16) * 32 + q4 * 8];
#pragma unroll
        for (int ni = 0; ni < 4; ++ni)
            bff[ni] = *(const bf16x8*)&Bs[(wn * 64 + ni * 16 + c16) * 32 + q4 * 8];
#pragma unroll
        for (int mi = 0; mi < 4; ++mi)
#pragma unroll
            for (int ni = 0; ni < 4; ++ni)
                acc[mi][ni] = __builtin_amdgcn_mfma_f32_16x16x32_bf16(af[mi], bff[ni],
                                                                     acc[mi][ni], 0, 0, 0);
    }
#pragma unroll
    for (int mi = 0; mi < 4; ++mi)
#pragma unroll
        for (int ni = 0; ni < 4; ++ni)
#pragma unroll
            for (int r = 0; r < 4; ++r) {
                const int row = m0 + wm * 64 + mi * 16 + q4 * 4 + r;
                const int col = n0 + wn * 64 + ni * 16 + c16;
                float v = acc[mi][ni][r];
                if (ACT == 1) {
                    v += bias[col];
                    v = 0.5f * v * (1.0f + erff(v * 0.70710678118654752f));
                }
                C[(size_t)row * N + col] = v;
            }
}

// ---------------- fused causal conv(K=4) + silu (+ row l2norm), LDS-tiled
template <int DO_NORM, int EMIT_F32, int EMIT_BF>
__global__ __launch_bounds__(256) void convql_k(const float* __restrict__ X,
                                                const float* __restrict__ cw,
                                                float* __restrict__ Y,
                                                ushort_t* __restrict__ Ybf) {
    __shared__ float xs[35 * 256];
    const int bid = blockIdx.x;
    const int h = bid & 3, lt = (bid >> 2) & 63, b = bid >> 8;
    const int t = threadIdx.x;
    const int l0 = lt << 5;
    const int cg = (h << 8) | t;
    for (int e = t; e < 35 * 256; e += 256) {
        const int r = e >> 8, c = e & 255;
        const int gl = l0 + r - 3;
        xs[e] = (gl >= 0) ? X[((size_t)(b * L_) + gl) * 3072 + (h << 8) + c] : 0.f;
    }
    const float w0 = cw[cg * 4 + 0], w1 = cw[cg * 4 + 1];
    const float w2 = cw[cg * 4 + 2], w3 = cw[cg * 4 + 3];
    __syncthreads();
    float yr[32];
#pragma unroll
    for (int l = 0; l < 32; ++l) {
        const float a = xs[(l + 0) * 256 + t] * w0 + xs[(l + 1) * 256 + t] * w1 +
                        xs[(l + 2) * 256 + t] * w2 + xs[(l + 3) * 256 + t] * w3;
        yr[l] = a / (1.f + expf(-a));
    }
    if (DO_NORM) {
        __syncthreads();
#pragma unroll
        for (int l = 0; l < 32; ++l) xs[l * 256 + t] = yr[l];
        __syncthreads();
        const int wv = t >> 6, lane = t & 63;
#pragma unroll
        for (int ri = 0; ri < 8; ++ri) {
            const int r = wv * 8 + ri;
            float4 v = *(float4*)&xs[r * 256 + lane * 4];
            float ss = v.x * v.x + v.y * v.y + v.z * v.z + v.w * v.w;
            ss = wred(ss);
            ss = __shfl(ss, 0);
            const float s = rsqrtf(ss + 1e-6f);
            v.x *= s; v.y *= s; v.z *= s; v.w *= s;
            const size_t go = ((size_t)(b * L_) + l0 + r) * 1024 + (h << 8) + lane * 4;
            if (EMIT_F32) *(float4*)&Y[go] = v;
            if (EMIT_BF) {
                ushort4 p;
                p.x = f2bs(v.x); p.y = f2bs(v.y); p.z = f2bs(v.z); p.w = f2bs(v.w);
                *(ushort4*)&Ybf[go] = p;
            }
        }
    } else {
#pragma unroll
        for (int l = 0; l < 32; ++l)
            if (EMIT_F32) Y[((size_t)(b * L_) + l0 + l) * 1024 + cg] = yr[l];
    }
}

// ---------------- fused FIR branches (K=1,3,7,31), LDS-tiled, one read of v
__global__ __launch_bounds__(256) void fir_k(const float* __restrict__ V,
                                             const float* __restrict__ w1w,
                                             const float* __restrict__ w3w,
                                             const float* __restrict__ w7w,
                                             const float* __restrict__ w31w,
                                             float* __restrict__ o1,
                                             float* __restrict__ o3,
                                             float* __restrict__ o7,
                                             float* __restrict__ o31) {
    __shared__ float xs[62 * 256];
    const int bid = blockIdx.x;
    const int h = bid & 3, lt = (bid >> 2) & 63, b = bid >> 8;
    const int t = threadIdx.x;
    const int l0 = lt << 5;
    const int cg = (h << 8) | t;
    for (int e = t; e < 62 * 256; e += 256) {
        const int r = e >> 8, c = e & 255;
        const int gl = l0 + r - 30;
        xs[e] = (gl >= 0) ? V[((size_t)(b * L_) + gl) * 1024 + (h << 8) + c] : 0.f;
    }
    float lw31[31], lw7[7], lw3[3];
#pragma unroll
    for (int j = 0; j < 31; ++j) lw31[j] = w31w[cg * 31 + j];
#pragma unroll
    for (int j = 0; j < 7; ++j) lw7[j] = w7w[cg * 7 + j];
#pragma unroll
    for (int j = 0; j < 3; ++j) lw3[j] = w3w[cg * 3 + j];
    const float lw1 = w1w[cg];
    __syncthreads();
    for (int l = 0; l < 32; ++l) {
        float a31 = 0.f, a7 = 0.f, a3 = 0.f, v = 0.f;
#pragma unroll
        for (int j = 0; j < 31; ++j) {
            v = xs[(l + j) * 256 + t];
            a31 += v * lw31[j];
            if (j >= 24) a7 += v * lw7[j - 24];
            if (j >= 28) a3 += v * lw3[j - 28];
        }
        const size_t go = ((size_t)(b * L_) + l0 + l) * 1024 + cg;
        o31[go] = a31;
        o7[go] = a7;
        o3[go] = a3;
        o1[go] = v * lw1;
    }
}

// ------------------- beta = sigmoid(hs @ b_w); also emit gate_in hs-part (bf16)
__global__ __launch_bounds__(64) void beta_k(const float* __restrict__ hs,
                                             const float* __restrict__ bw,
                                             float* __restrict__ beta,
                                             ushort_t* __restrict__ gin) {
    const int row = blockIdx.x;
    const int lane = threadIdx.x;
    float a0 = 0, a1 = 0, a2 = 0, a3 = 0;
    const float* hp = hs + (size_t)row * D_;
    ushort_t* gp = gin + (size_t)row * 1120;
    for (int c = lane; c < D_; c += 64) {
        const float x = hp[c];
        gp[c] = f2bs(x);
        a0 += x * bw[c * 4 + 0];
        a1 += x * bw[c * 4 + 1];
        a2 += x * bw[c * 4 + 2];
        a3 += x * bw[c * 4 + 3];
    }
    a0 = wred(a0); a1 = wred(a1); a2 = wred(a2); a3 = wred(a3);
    if (lane == 0) {
        float* o = beta + (size_t)row * 4;
        o[0] = 1.f / (1.f + expf(-a0));
        o[1] = 1.f / (1.f + expf(-a1));
        o[2] = 1.f / (1.f + expf(-a2));
        o[3] = 1.f / (1.f + expf(-a3));
    }
}

// --------------- fused MFMA delta-prep. Exports ALL scan operands in
// MFMA-fragment-linear layouts (coalesced 16B/lane reads in the scan):
//   qfr/wfr[((cb*2+wv)*8+s)*512 + lane*8]   (A-frags, rows wv*16+l16)
//   atfr[(cb*2+wv)*512 + lane*8]            (attn A-frag)
//   ktfr[(cb*16+tc)*512 + lane*8]           (kT A-frag per c-tile)
//   ufr[((cb*16+nt)*2+mi)*256 + lane*4]     (fp32 C-layout slices)
__global__ __launch_bounds__(256) void prep2_k(const ushort_t* __restrict__ qbf,
                                               const ushort_t* __restrict__ kbf,
                                               const float* __restrict__ vg,
                                               const float* __restrict__ beta,
                                               ushort_t* __restrict__ qfr,
                                               ushort_t* __restrict__ wfr,
                                               float* __restrict__ ufr,
                                               ushort_t* __restrict__ atfr,
                                               ushort_t* __restrict__ ktfr) {
    __shared__ ushort_t k_lds[32 * 264];   // k rows; reused as w_s later
    __shared__ ushort_t kT_lds[256 * 32];  // swizzled: seg s at (s ^ ((c>>1)&3))
    __shared__ ushort_t vT_lds[256 * 32];  // same swizzle
    __shared__ float Am[32 * 33];
    __shared__ float Tm[32 * 33];
    __shared__ ushort_t Tb[32 * 40];       // T' bf16
    __shared__ ushort_t at_s[32 * 40];     // attn bf16 (row-major, 16B-aligned rows)
    __shared__ float beta_s[32];
    const int bid = blockIdx.x;  // bh*NC + ci
    const int bh = bid >> 6, ci = bid & 63;
    const int b = bh >> 2, h = bh & 3;
    const int t = threadIdx.x;
    const int wv = t >> 6, lane = t & 63;
    const int mi = wv & 1, ni = wv >> 1;
    const int l16 = lane & 15, quad = lane >> 4;
    const size_t cb = (size_t)bid;
    const size_t grow = ((size_t)(b * L_ + ci * 32)) * 1024 + (h << 8);
    const f32x4 z4 = {0.f, 0.f, 0.f, 0.f};

    if (t < 32) beta_s[t] = beta[(size_t)(b * L_ + ci * 32 + t) * 4 + h];
    // stage k rows (plain, padded)
#pragma unroll
    for (int j = 0; j < 4; ++j) {
        const int idx = j * 2048 + t * 8, r = idx >> 8, c = idx & 255;
        *(u16x8*)&k_lds[r * 264 + c] = *(const u16x8*)&kbf[grow + (size_t)r * 1024 + c];
    }
    // build vT (bf16, swizzled) from global v
#pragma unroll
    for (int j = 0; j < 8; ++j) {
        const int e = j * 1024 + t * 4, r = e >> 8, c = e & 255;
        const float4 v4 = *(const float4*)&vg[grow + (size_t)r * 1024 + c];
        const float vv[4] = {v4.x, v4.y, v4.z, v4.w};
#pragma unroll
        for (int x = 0; x < 4; ++x) {
            const int cc = c + x;
            const int sp = (r >> 3) ^ ((cc >> 1) & 3);
            vT_lds[cc * 32 + sp * 8 + (r & 7)] = f2bs(vv[x]);
        }
    }
    // G = k@kT and attn = q@kT from global register fragments; waves 0,1 export qfr
    f32x4 g = z4, atv = z4;
#pragma unroll
    for (int s = 0; s < 8; ++s) {
        const bf16x8 a =
            *(const bf16x8*)&kbf[grow + (size_t)(mi * 16 + l16) * 1024 + s * 32 + (quad << 3)];
        const bf16x8 bb =
            *(const bf16x8*)&kbf[grow + (size_t)(ni * 16 + l16) * 1024 + s * 32 + (quad << 3)];
        const bf16x8 qa =
            *(const bf16x8*)&qbf[grow + (size_t)(mi * 16 + l16) * 1024 + s * 32 + (quad << 3)];
        g = __builtin_amdgcn_mfma_f32_16x16x32_bf16(a, bb, g, 0, 0, 0);
        atv = __builtin_amdgcn_mfma_f32_16x16x32_bf16(qa, bb, atv, 0, 0, 0);
        if (ni == 0) *(bf16x8*)&qfr[((cb * 2 + mi) * 8 + s) * 512 + lane * 8] = qa;
    }
    __syncthreads();  // beta_s + k_lds + vT visible
    // Am / Tm init + attn -> at_s
#pragma unroll
    for (int r = 0; r < 4; ++r) {
        const int row = mi * 16 + (quad << 2) + r;
        const int col = ni * 16 + l16;
        Am[row * 33 + col] = (col < row) ? -beta_s[row] * g[r] : 0.f;
        Tm[row * 33 + col] = (row == col) ? 1.f : 0.f;
        at_s[row * 40 + col] = (col <= row) ? f2bs(atv[r]) : (ushort_t)0;
    }
    // build kT (swizzled) from k_lds
#pragma unroll
    for (int j = 0; j < 8; ++j) {
        const int e = j * 1024 + t * 4, r = e >> 8, c = e & 255;
#pragma unroll
        for (int x = 0; x < 4; ++x) {
            const int cc = c + x;
            const int sp = (r >> 3) ^ ((cc >> 1) & 3);
            kT_lds[cc * 32 + sp * 8 + (r & 7)] = k_lds[r * 264 + cc];
        }
    }
    __syncthreads();
    // export atfr (waves 0,1) and ktfr (all waves, 4 c-tiles each)
    if (wv < 2) {
        const u16x8 av = *(const u16x8*)&at_s[(wv * 16 + l16) * 40 + (quad << 3)];
        *(u16x8*)&atfr[(cb * 2 + wv) * 512 + lane * 8] = av;
    }
#pragma unroll
    for (int j2 = 0; j2 < 4; ++j2) {
        const int tc = wv * 4 + j2;
        const int c = tc * 16 + l16;
        const int sp = quad ^ ((c >> 1) & 3);
        *(u16x8*)&ktfr[(cb * 16 + tc) * 512 + lane * 8] = *(const u16x8*)&kT_lds[c * 32 + sp * 8];
    }
    // forward substitution: T[i] += sum_{j<i} A[i][j] T[j]
    for (int i = 1; i < 32; ++i) {
        if (t < 32) {
            float s = 0.f;
            for (int j = 0; j < i; ++j) s += Am[i * 33 + j] * Tm[j * 33 + t];
            Tm[i * 33 + t] += s;
        }
        __syncthreads();
    }
    // Tb = bf16(T * beta_col)
#pragma unroll
    for (int j = 0; j < 4; ++j) {
        const int e = j * 256 + t, i = e >> 5, jj = e & 31;
        Tb[i * 40 + jj] = f2bs(Tm[i * 33 + jj] * beta_s[jj]);
    }
    __syncthreads();
    // w = T'@k -> w_s (k_lds reuse); u = T'@v -> ufr (fragment layout direct)
    const bf16x8 tf = *(const bf16x8*)&Tb[(mi * 16 + l16) * 40 + (quad << 3)];
#pragma unroll
    for (int j = 0; j < 8; ++j) {
        const int nt = ni * 8 + j;
        const int d = (nt << 4) + l16;
        const int sp = quad ^ ((d >> 1) & 3);
        const bf16x8 kb = *(const bf16x8*)&kT_lds[d * 32 + (sp << 3)];
        const bf16x8 vb = *(const bf16x8*)&vT_lds[d * 32 + (sp << 3)];
        const f32x4 wacc = __builtin_amdgcn_mfma_f32_16x16x32_bf16(tf, kb, z4, 0, 0, 0);
        const f32x4 uacc = __builtin_amdgcn_mfma_f32_16x16x32_bf16(tf, vb, z4, 0, 0, 0);
        *(float4*)&ufr[((cb * 16 + nt) * 2 + mi) * 256 + lane * 4] =
            make_float4(uacc[0], uacc[1], uacc[2], uacc[3]);
#pragma unroll
        for (int r = 0; r < 4; ++r) {
            const int row = mi * 16 + (quad << 2) + r;
            k_lds[row * 264 + d] = f2bs(wacc[r]);  // w_s
        }
    }
    __syncthreads();
    // export wfr (waves 0,1)
    if (wv < 2) {
#pragma unroll
        for (int s = 0; s < 8; ++s) {
            const u16x8 wv8 = *(const u16x8*)&k_lds[(wv * 16 + l16) * 264 + s * 32 + (quad << 3)];
            *(u16x8*)&wfr[((cb * 2 + wv) * 8 + s) * 512 + lane * 8] = wv8;
        }
    }
}

// ---------------------- MFMA scan: fragment-linear coalesced loads, reg double-buffer,
// S-mirror double-buffered in LDS (2 barriers/chunk, lgkm-only)
__global__ __launch_bounds__(256, 1) void scan5_k(const ushort_t* __restrict__ qfr,
                                                  const ushort_t* __restrict__ wfr,
                                                  const float* __restrict__ ufr,
                                                  const ushort_t* __restrict__ atfr,
                                                  const ushort_t* __restrict__ ktfr,
                                                  float* __restrict__ dlt) {
    __shared__ ushort_t uh_lds[16 * 40];
    __shared__ ushort_t S_lds[2][16 * 264];
    const int t = threadIdx.x;
    const int wv = t >> 6, lane = t & 63;
    const int bh = blockIdx.x & 7, tile = blockIdx.x >> 3;
    const int b = bh >> 2, h = bh & 3;
    const int l16 = lane & 15, quad = lane >> 4;
    for (int e = t; e < 16 * 264; e += 256) S_lds[0][e] = 0;

    f32x4 Sacc[8];
#pragma unroll
    for (int j = 0; j < 8; ++j) {
        f32x4 z = {0.f, 0.f, 0.f, 0.f};
        Sacc[j] = z;
    }

    bf16x8 wfA[8], qfA[8], atfA, ktA[8];
    bf16x8 wfB[8], qfB[8], atfB, ktB[8];
    float uvA[4], uvB[4];

    auto loadf = [&](int ci, bf16x8* wf, bf16x8* qf, bf16x8& atf, float* uv, bf16x8* ktf) {
        const size_t cb = (size_t)(bh * NC + ci);
        if (wv < 2) {
            const ushort_t* wsrc = wfr + (cb * 2 + wv) * 8 * 512;
            const ushort_t* qsrc = qfr + (cb * 2 + wv) * 8 * 512;
#pragma unroll
            for (int s = 0; s < 8; ++s) {
                wf[s] = *(const bf16x8*)&wsrc[s * 512 + lane * 8];
                qf[s] = *(const bf16x8*)&qsrc[s * 512 + lane * 8];
            }
            atf = *(const bf16x8*)&atfr[(cb * 2 + wv) * 512 + lane * 8];
            const float4 u4 = *(const float4*)&ufr[((cb * 16 + tile) * 2 + wv) * 256 + lane * 4];
            uv[0] = u4.x; uv[1] = u4.y; uv[2] = u4.z; uv[3] = u4.w;
        } else {
            const ushort_t* ksrc = ktfr + cb * 16 * 512;
#pragma unroll
            for (int j = 0; j < 8; ++j) {
                const int tc = ((wv - 2) << 3) + j;
                ktf[j] = *(const bf16x8*)&ksrc[tc * 512 + lane * 8];
            }
        }
    };
    auto sfrag = [&](int p, int k0) -> bf16x8 {
        return *(const bf16x8*)&S_lds[p][l16 * 264 + k0 + (quad << 3)];
    };
    auto uhfrag = [&]() -> bf16x8 {
        return *(const bf16x8*)&uh_lds[l16 * 40 + (quad << 3)];
    };
    auto compute = [&](int ci, bf16x8* wf, bf16x8* qf, bf16x8& atf, float* uv, bf16x8* ktf) {
        const int p = ci & 1;
        const size_t gbase = ((size_t)(b * L_ + ci * 32)) * D_ + (h << 8);
        if (wv < 2) {
            f32x4 a0 = {0.f, 0.f, 0.f, 0.f}, a1 = {0.f, 0.f, 0.f, 0.f};
#pragma unroll
            for (int s = 0; s < 8; s += 2) {
                a0 = __builtin_amdgcn_mfma_f32_16x16x32_bf16(wf[s], sfrag(p, s * 32), a0, 0, 0, 0);
                a1 = __builtin_amdgcn_mfma_f32_16x16x32_bf16(wf[s + 1], sfrag(p, s * 32 + 32), a1,
                                                             0, 0, 0);
            }
            ushort4 up;
            up.x = f2bs(uv[0] - a0[0] - a1[0]);
            up.y = f2bs(uv[1] - a0[1] - a1[1]);
            up.z = f2bs(uv[2] - a0[2] - a1[2]);
            up.w = f2bs(uv[3] - a0[3] - a1[3]);
            *(ushort4*)&uh_lds[l16 * 40 + (wv << 4) + (quad << 2)] = up;
        }
        LGKM0_BAR();  // uh visible
        if (wv < 2) {
            f32x4 o0 = {0.f, 0.f, 0.f, 0.f}, o1 = {0.f, 0.f, 0.f, 0.f};
#pragma unroll
            for (int s = 0; s < 8; s += 2) {
                o0 = __builtin_amdgcn_mfma_f32_16x16x32_bf16(qf[s], sfrag(p, s * 32), o0, 0, 0, 0);
                o1 = __builtin_amdgcn_mfma_f32_16x16x32_bf16(qf[s + 1], sfrag(p, s * 32 + 32), o1,
                                                             0, 0, 0);
            }
            o0 = __builtin_amdgcn_mfma_f32_16x16x32_bf16(atf, uhfrag(), o0, 0, 0, 0);
#pragma unroll
            for (int r = 0; r < 4; ++r)
                dlt[gbase + (size_t)((wv << 4) + (quad << 2) + r) * D_ + (tile << 4) + l16] =
                    o0[r] + o1[r];
        } else {
            const bf16x8 uf = uhfrag();
#pragma unroll
            for (int j = 0; j < 8; ++j)
                Sacc[j] = __builtin_amdgcn_mfma_f32_16x16x32_bf16(ktf[j], uf, Sacc[j], 0, 0, 0);
            // snapshot S (post-chunk) into the other buffer
#pragma unroll
            for (int j = 0; j < 8; ++j) {
                const int c0 = ((((wv - 2) << 3) + j) << 4) + (quad << 2);
                ushort4 pk;
                pk.x = f2bs(Sacc[j][0]);
                pk.y = f2bs(Sacc[j][1]);
                pk.z = f2bs(Sacc[j][2]);
                pk.w = f2bs(Sacc[j][3]);
                *(ushort4*)&S_lds[p ^ 1][l16 * 264 + c0] = pk;
            }
        }
        LGKM0_BAR();  // mirror ready; uh free for next chunk
    };

    loadf(0, wfA, qfA, atfA, uvA, ktA);
    LGKM0_BAR();  // S zero-init visible
    for (int ci = 0; ci < NC; ci += 2) {
        loadf(ci + 1, wfB, qfB, atfB, uvB, ktB);
        compute(ci, wfA, qfA, atfA, uvA, ktA);
        if (ci + 2 < NC) loadf(ci + 2, wfA, qfA, atfA, uvA, ktA);
        compute(ci + 1, wfB, qfB, atfB, uvB, ktB);
    }
}

// ---------------- branch stats -> gate_in stat columns (bf16)
__global__ __launch_bounds__(64) void stats_k(const float* __restrict__ f1,
                                              const float* __restrict__ f3,
                                              const float* __restrict__ f7,
                                              const float* __restrict__ f31,
                                              const float* __restrict__ dl,
                                              const float* __restrict__ vv,
                                              ushort_t* __restrict__ gin) {
    const int row = blockIdx.x;  // (b*L+l)*H + h
    const int lane = threadIdx.x;
    const float* ptrs[6] = {f1, f3, f7, f31, dl, vv};
    const size_t base = (size_t)row * 256;
    ushort_t* gp = gin + (size_t)(row >> 2) * 1120 + 1024 + (row & 3) * 24;
    for (int br = 0; br < 6; ++br) {
        const float4 x = *(const float4*)&ptrs[br][base + lane * 4];
        float s1 = x.x + x.y + x.z + x.w;
        float s2 = x.x * x.x + x.y * x.y + x.z * x.z + x.w * x.w;
        float sa = fabsf(x.x) + fabsf(x.y) + fabsf(x.z) + fabsf(x.w);
        s1 = wred(s1); s2 = wred(s2); sa = wred(sa);
        if (lane == 0) {
            const float m = s1 / 256.f;
            float var = (s2 - 256.f * m * m) / 255.f;
            if (var < 0.f) var = 0.f;
            gp[br * 4 + 0] = f2bs(m);
            gp[br * 4 + 1] = f2bs(sqrtf(var));
            gp[br * 4 + 2] = f2bs(sa / 256.f);
            gp[br * 4 + 3] = f2bs(sqrtf(s2));
        }
    }
}

// ---------------------------------------------- logits -> softmax weights
__global__ __launch_bounds__(256) void wts_k(const float* __restrict__ hg,
                                             const float* __restrict__ w2,
                                             const float* __restrict__ b2,
                                             const float* __restrict__ glt,
                                             float* __restrict__ wts) {
    const int row = blockIdx.x;
    const int h = threadIdx.x >> 6, lane = threadIdx.x & 63;
    float hv[16];
    const float* hp = hg + (size_t)row * 1024;
#pragma unroll
    for (int ii = 0; ii < 16; ++ii) hv[ii] = hp[lane + 64 * ii];
    float lg[6];
#pragma unroll
    for (int s = 0; s < 6; ++s) {
        const int j = h * 6 + s;
        float acc = 0.f;
#pragma unroll
        for (int ii = 0; ii < 16; ++ii) acc += hv[ii] * w2[(size_t)(lane + 64 * ii) * 24 + j];
        lg[s] = wred(acc);
    }
    if (lane == 0) {
        const float temp = log1pf(expf(glt[h])) + 0.5f;
        float mx = -1e30f;
#pragma unroll
        for (int s = 0; s < 6; ++s) {
            lg[s] = (lg[s] + b2[h * 6 + s]) / temp;
            mx = fmaxf(mx, lg[s]);
        }
        float se = 0.f;
#pragma unroll
        for (int s = 0; s < 6; ++s) {
            lg[s] = expf(lg[s] - mx);
            se += lg[s];
        }
        float* o = &wts[(size_t)row * 24 + h * 6];
        const float inv = 1.f / se;
#pragma unroll
        for (int s = 0; s < 6; ++s) o[s] = lg[s] * inv;
    }
}

// -------------------------------------- fused = RMSNorm(sum ws*branch) * onorm_w (bf16 out)
__global__ __launch_bounds__(1024) void fuse_k(const float* __restrict__ f1,
                                               const float* __restrict__ f3,
                                               const float* __restrict__ f7,
                                               const float* __restrict__ f31,
                                               const float* __restrict__ dl,
                                               const float* __restrict__ vv,
                                               const float* __restrict__ wts,
                                               const float* __restrict__ onw,
                                               ushort_t* __restrict__ fused) {
    __shared__ float wloc[24];
    __shared__ float psum[16];
    const int row = blockIdx.x, t = threadIdx.x;
    if (t < 24) wloc[t] = wts[(size_t)row * 24 + t];
    __syncthreads();
    const int h = t >> 8, dd = t & 255;
    const size_t idx = (size_t)row * 1024 + t;
    const float* ptrs[6] = {f1, f3, f7, f31, dl, vv};
    float f = 0.f;
#pragma unroll
    for (int br = 0; br < 6; ++br) f += wloc[h * 6 + br] * ptrs[br][idx];
    float ss = wred(f * f);
    const int wave = t >> 6;
    if ((t & 63) == 0) psum[wave] = ss;
    __syncthreads();
    const float tot = psum[h * 4 + 0] + psum[h * 4 + 1] + psum[h * 4 + 2] + psum[h * 4 + 3];
    const float scale = rsqrtf(tot / 256.f + 1e-5f);
    fused[idx] = f2bs(f * scale * onw[dd]);
}

// ================================================================ launch
extern "C" void kernel_launch(void* const* d_in, const int* in_sizes, int n_in,
                              void* d_out, int out_size, void* d_ws, size_t ws_size,
                              hipStream_t stream) {
    const float* hs   = (const float*)d_in[0];
    const float* q_w  = (const float*)d_in[1];
    const float* k_w  = (const float*)d_in[2];
    const float* v_w  = (const float*)d_in[3];
    const float* b_w  = (const float*)d_in[4];
    const float* qc_w = (const float*)d_in[5];
    const float* kc_w = (const float*)d_in[6];
    const float* vc_w = (const float*)d_in[7];
    const float* f1w  = (const float*)d_in[8];
    const float* f3w  = (const float*)d_in[9];
    const float* f7w  = (const float*)d_in[10];
    const float* f31w = (const float*)d_in[11];
    const float* w1   = (const float*)d_in[12];
    const float* b1   = (const float*)d_in[13];
    const float* w2   = (const float*)d_in[14];
    const float* b2   = (const float*)d_in[15];
    const float* glt  = (const float*)d_in[16];
    const float* onw  = (const float*)d_in[17];
    const float* o_w  = (const float*)d_in[18];
    float* out = (float*)d_out;

    const size_t SZ = (size_t)B_ * L_ * D_;  // 4,194,304
    float* qlin = (float*)d_ws;       // qkv[4096][3072] spans 3*SZ; f1b after scan
    float* klin = qlin + SZ;          // ktfr+qfr bf16 [prep2..scan]; f3b after scan
    float* vlin = klin + SZ;          // f7b after scan
    float* qbuf = vlin + SZ;          // gin_bf (bf16) [beta_k .. gate gemm]
    float* kbuf = qbuf + SZ;          // kbf bf16 [conv..prep2]; hgate fp32; fused_bf
    float* vbuf = kbuf + SZ;          // v fp32 (silu)
    float* f31b = vbuf + SZ;          // qwT/kwT/vwT early; qbf bf16 [conv..prep2]; f31 after
    float* wb   = f31b + SZ;          // wfr bf16 [prep2..scan]; w1T after scan
    float* ub   = wb + SZ;            // ufr fp32 [prep2..scan]; owT after
    float* dlt  = ub + SZ;            // hs_bf early; dlt fp32 [scan..fuse]
    float* beta = dlt + SZ;
    float* attn = beta + (size_t)B_ * L_ * H_;   // atfr bf16
    float* f1b = qlin;
    float* f3b = klin;
    float* f7b = vlin;
    float* hgate = kbuf;
    float* qkv = qlin;  // [4096][3072]
    float* wts = attn + (size_t)B_ * H_ * NC * 1024;

    // bf16 aliases
    ushort_t* hs_bf = (ushort_t*)dlt;
    ushort_t* qwT = (ushort_t*)f31b;
    ushort_t* kwT = (ushort_t*)f31b + 1048576;
    ushort_t* vwT = (ushort_t*)f31b + 2097152;
    ushort_t* qbf = (ushort_t*)f31b + 3145728;
    ushort_t* kbf = (ushort_t*)kbuf;
    ushort_t* gin_bf = (ushort_t*)qbuf;
    ushort_t* w1T = (ushort_t*)(wb + 2359296);
    ushort_t* owT = (ushort_t*)ub;
    ushort_t* fused_bf = (ushort_t*)kbuf;
    ushort_t* ktfr = (ushort_t*)klin;            // SZ ushorts
    ushort_t* qfr = (ushort_t*)klin + SZ;        // second half of klin region
    ushort_t* wfr = (ushort_t*)wb;
    float* ufr = ub;
    ushort_t* atfr = (ushort_t*)attn;

    const int M = B_ * L_;  // 4096

    // weight transposes + activation cast
    tcast_k<<<dim3(32, 32), 256, 0, stream>>>(q_w, qwT, 1024, 1024);
    tcast_k<<<dim3(32, 32), 256, 0, stream>>>(k_w, kwT, 1024, 1024);
    tcast_k<<<dim3(32, 32), 256, 0, stream>>>(v_w, vwT, 1024, 1024);
    cast_k<<<4096, 256, 0, stream>>>(hs, hs_bf);
    // fused q|k|v projection: qkv[M][3072]
    gemm_bf<0><<<dim3(24, 32), 256, 0, stream>>>(hs_bf, qwT, nullptr, qkv, M, 3072, 1024);
    beta_k<<<M, 64, 0, stream>>>(hs, b_w, beta, gin_bf);
    // fused conv+silu(+l2norm): q,k emit bf16 only; v emits fp32
    convql_k<1, 0, 1><<<512, 256, 0, stream>>>(qkv + 0,    qc_w, nullptr, qbf);
    convql_k<1, 0, 1><<<512, 256, 0, stream>>>(qkv + 1024, kc_w, nullptr, kbf);
    convql_k<0, 1, 0><<<512, 256, 0, stream>>>(qkv + 2048, vc_w, vbuf, nullptr);
    // chunkwise delta rule
    prep2_k<<<B_ * H_ * NC, 256, 0, stream>>>(qbf, kbf, vbuf, beta, qfr, wfr, ufr, atfr, ktfr);
    scan5_k<<<128, 256, 0, stream>>>(qfr, wfr, ufr, atfr, ktfr, dlt);
    // fused FIR branches
    fir_k<<<512, 256, 0, stream>>>(vbuf, f1w, f3w, f7w, f31w, f1b, f3b, f7b, f31b);
    // gate
    stats_k<<<M * H_, 64, 0, stream>>>(f1b, f3b, f7b, f31b, dlt, vbuf, gin_bf);
    tcast_k<<<dim3(32, 35), 256, 0, stream>>>(w1, w1T, 1120, 1024);
    gemm_bf<1><<<dim3(8, 32), 256, 0, stream>>>(gin_bf, w1T, b1, hgate, M, 1024, 1120);
    wts_k<<<M, 256, 0, stream>>>(hgate, w2, b2, glt, wts);
    fuse_k<<<M, 1024, 0, stream>>>(f1b, f3b, f7b, f31b, dlt, vbuf, wts, onw, fused_bf);
    // output projection
    tcast_k<<<dim3(32, 32), 256, 0, stream>>>(o_w, owT, 1024, 1024);
    gemm_bf<0><<<dim3(8, 32), 256, 0, stream>>>(fused_bf, owT, nullptr, out, M, 1024, 1024);
}